// Round 1
// baseline (9903.249 us; speedup 1.0000x reference)
//
#include <hip/hip_runtime.h>
#include <hip/hip_bf16.h>
#include <math.h>

// ---------------- constants ----------------
#define B_   8
#define S_   1024
#define D_   768
#define H_   12
#define HD_  64
#define L_   12
#define F_   3072
#define NTOK 8192   // B_*S_

typedef __bf16 bf16x8 __attribute__((ext_vector_type(8)));
typedef float  f32x4  __attribute__((ext_vector_type(4)));

static __device__ __forceinline__ unsigned short f2bf_bits(float f) {
    __hip_bfloat16 h = __float2bfloat16(f);
    return __builtin_bit_cast(unsigned short, h);
}
static __device__ __forceinline__ float bf2f(unsigned short u) {
    unsigned int t = ((unsigned int)u) << 16;
    return __builtin_bit_cast(float, t);
}
static __device__ __forceinline__ void gload16(const void* g, void* l) {
    __builtin_amdgcn_global_load_lds(
        (__attribute__((address_space(1))) void*)g,
        (__attribute__((address_space(3))) void*)l, 16, 0, 0);
}

// ---------------- weight prep: fp32 [R][C] -> bf16 transposed [C][R] ----------------
// One launch per layer covers Wqkv (per-head), Wo, W1, W2 into wbuf.
// wbuf element offsets: wqkv_t=0 (2304x768), wo_t=1769472 (768x768),
//                       w1_t=2359296 (3072x768), w2_t=4718592 (768x3072)
__global__ __launch_bounds__(256)
void prep_layer_kernel(const float* __restrict__ Wq, const float* __restrict__ Wk,
                       const float* __restrict__ Wv, const float* __restrict__ Wo,
                       const float* __restrict__ W1, const float* __restrict__ W2,
                       int l, __hip_bfloat16* __restrict__ wbuf)
{
    const int id = blockIdx.x;   // 0..1727
    const float* src; __hip_bfloat16* dst;
    int R, C, r0, c0;
    if (id < 432) {                       // q/k/v heads: src [768][64] per (which,h)
        int dtile = id % 12, t = id / 12; // t = which*12 + h
        int which = t / 12, h = t % 12;
        src = (which == 0 ? Wq : which == 1 ? Wk : Wv) + (size_t)(l*12 + h) * 768 * 64;
        dst = wbuf + (size_t)(which*768 + h*64) * 768;
        R = 768; C = 64; r0 = dtile * 64; c0 = 0;
    } else if (id < 576) {                // Wo: [768][768]
        int t = id - 432;
        src = Wo + (size_t)l * 768 * 768;
        dst = wbuf + 1769472;
        R = 768; C = 768; r0 = (t / 12) * 64; c0 = (t % 12) * 64;
    } else if (id < 1152) {               // W1: [768][3072]
        int t = id - 576;
        src = W1 + (size_t)l * 768 * 3072;
        dst = wbuf + 2359296;
        R = 768; C = 3072; r0 = (t % 12) * 64; c0 = (t / 12) * 64;
    } else {                              // W2: [3072][768]
        int t = id - 1152;
        src = W2 + (size_t)l * 3072 * 768;
        dst = wbuf + 4718592;
        R = 3072; C = 768; r0 = (t / 12) * 64; c0 = (t % 12) * 64;
    }
    __shared__ float tile[64][65];
    for (int i = threadIdx.x; i < 4096; i += 256) {
        int rr = i >> 6, cc = i & 63;
        tile[rr][cc] = src[(size_t)(r0 + rr) * C + (c0 + cc)];
    }
    __syncthreads();
    for (int i = threadIdx.x; i < 4096; i += 256) {
        int cc = i >> 6, rr = i & 63;
        dst[(size_t)(c0 + cc) * R + (r0 + rr)] = __float2bfloat16(tile[rr][cc]);
    }
}

__global__ __launch_bounds__(256)
void prep_bqkv_kernel(const float* __restrict__ bq, const float* __restrict__ bk,
                      const float* __restrict__ bv, float* __restrict__ bqkv)
{
    int i = blockIdx.x * 256 + threadIdx.x;   // < 12*2304
    int l = i / 2304, c = i % 2304;
    int which = c / 768, hk = c % 768;
    const float* src = which == 0 ? bq : which == 1 ? bk : bv;
    bqkv[i] = src[l*768 + hk];
}

// ---------------- embedding + LN -> x (fp32) ----------------
__global__ __launch_bounds__(256)
void embed_ln_kernel(const int* __restrict__ tokens, const float* __restrict__ tok_emb,
                     const float* __restrict__ pos_emb, const float* __restrict__ gam,
                     const float* __restrict__ bet, float* __restrict__ x)
{
    const int row  = blockIdx.x*4 + (threadIdx.x >> 6);
    const int lane = threadIdx.x & 63;
    const int s    = row & (S_-1);
    const int tok  = tokens[row];
    const float* te = tok_emb + (size_t)tok * D_;
    const float* pe = pos_emb + (size_t)s   * D_;
    float v[12]; float s1 = 0.f, s2 = 0.f;
#pragma unroll
    for (int c = 0; c < 3; ++c) {
        const int base = c*256 + lane*4;
        float4 a = *(const float4*)(te + base);
        float4 p = *(const float4*)(pe + base);
        float t0 = a.x+p.x, t1 = a.y+p.y, t2 = a.z+p.z, t3 = a.w+p.w;
        v[c*4+0]=t0; v[c*4+1]=t1; v[c*4+2]=t2; v[c*4+3]=t3;
        s1 += t0+t1+t2+t3;
        s2 += t0*t0 + t1*t1 + t2*t2 + t3*t3;
    }
#pragma unroll
    for (int off = 32; off > 0; off >>= 1) { s1 += __shfl_xor(s1, off); s2 += __shfl_xor(s2, off); }
    const float mean = s1 * (1.f/768.f);
    const float rstd = rsqrtf(s2*(1.f/768.f) - mean*mean + 1e-5f);
    float* xr = x + (size_t)row * D_;
#pragma unroll
    for (int c = 0; c < 3; ++c) {
        const int base = c*256 + lane*4;
        float4 g = *(const float4*)(gam + base);
        float4 bb = *(const float4*)(bet + base);
        float4 o;
        o.x = (v[c*4+0]-mean)*rstd*g.x + bb.x;
        o.y = (v[c*4+1]-mean)*rstd*g.y + bb.y;
        o.z = (v[c*4+2]-mean)*rstd*g.z + bb.z;
        o.w = (v[c*4+3]-mean)*rstd*g.w + bb.w;
        *(float4*)(xr + base) = o;
    }
}

// ---------------- LN: x (fp32) -> xn (bf16) ----------------
__global__ __launch_bounds__(256)
void ln_kernel(const float* __restrict__ xin, const float* __restrict__ gam,
               const float* __restrict__ bet, __hip_bfloat16* __restrict__ out)
{
    const int row  = blockIdx.x*4 + (threadIdx.x >> 6);
    const int lane = threadIdx.x & 63;
    const float* xr = xin + (size_t)row * D_;
    float v[12]; float s1 = 0.f, s2 = 0.f;
#pragma unroll
    for (int c = 0; c < 3; ++c) {
        float4 t = *(const float4*)(xr + c*256 + lane*4);
        v[c*4+0]=t.x; v[c*4+1]=t.y; v[c*4+2]=t.z; v[c*4+3]=t.w;
        s1 += t.x+t.y+t.z+t.w;
        s2 += t.x*t.x + t.y*t.y + t.z*t.z + t.w*t.w;
    }
#pragma unroll
    for (int off = 32; off > 0; off >>= 1) { s1 += __shfl_xor(s1, off); s2 += __shfl_xor(s2, off); }
    const float mean = s1 * (1.f/768.f);
    const float rstd = rsqrtf(s2*(1.f/768.f) - mean*mean + 1e-5f);
    unsigned short* op = (unsigned short*)out + (size_t)row * D_;
#pragma unroll
    for (int c = 0; c < 3; ++c) {
        const int base = c*256 + lane*4;
        float4 g = *(const float4*)(gam + base);
        float4 bb = *(const float4*)(bet + base);
        ushort4 pk;
        pk.x = f2bf_bits((v[c*4+0]-mean)*rstd*g.x + bb.x);
        pk.y = f2bf_bits((v[c*4+1]-mean)*rstd*g.y + bb.y);
        pk.z = f2bf_bits((v[c*4+2]-mean)*rstd*g.z + bb.z);
        pk.w = f2bf_bits((v[c*4+3]-mean)*rstd*g.w + bb.w);
        *(ushort4*)(op + base) = pk;
    }
}

// ---------------- GEMM: C[M,N] = A[M,K](bf16) * Bt[N,K](bf16)^T + bias ----------------
// 128x128 tile, BK=64, 4 waves (2x2), mfma_f32_16x16x32_bf16, global_load_lds w16,
// XOR-swizzled linear LDS (slot ^= row&7), XCD-chunk blockIdx swizzle.
// EPI: 0 = store bf16 (qkv), 1 = gelu->bf16 (ffn1), 2 = outf += acc+bias (residual)
template<int EPI>
__global__ __launch_bounds__(256)
void gemm_kernel(const __hip_bfloat16* __restrict__ A,
                 const __hip_bfloat16* __restrict__ Bt,
                 const float* __restrict__ bias,
                 __hip_bfloat16* __restrict__ outb,
                 float* __restrict__ outf,
                 int M, int N, int K, int nTiles)
{
    __shared__ __hip_bfloat16 As[128*64];
    __shared__ __hip_bfloat16 Bs[128*64];

    const int tid  = threadIdx.x;
    const int lane = tid & 63;
    const int wid  = tid >> 6;

    const int nwg   = gridDim.x;
    const int chunk = nwg >> 3;
    const int bid   = blockIdx.x;
    const int swz   = (bid & 7) * chunk + (bid >> 3);
    const int m0 = (swz / nTiles) * 128;
    const int n0 = (swz % nTiles) * 128;

    // staging: wave w covers tile rows [w*32, w*32+32); lane -> (row=lane/8, slot=lane%8)
    const int srow = wid*32 + (lane >> 3);
    const int scol = ((lane & 7) ^ (srow & 7)) * 8;   // swizzled source column (elements)
    const __hip_bfloat16* aSrc = A  + (size_t)(m0 + srow) * K + scol;
    const __hip_bfloat16* bSrc = Bt + (size_t)(n0 + srow) * K + scol;
    char* aDst = (char*)As + wid*4096 + lane*16;
    char* bDst = (char*)Bs + wid*4096 + lane*16;

    f32x4 acc[4][4] = {};
    const int wm = wid >> 1, wn = wid & 1;
    const int cl = lane & 15, hi = lane >> 4;

    for (int kt = 0; kt < K; kt += 64) {
        __syncthreads();
#pragma unroll
        for (int i = 0; i < 4; ++i)
            gload16(aSrc + kt + (size_t)i*8*K, aDst + i*1024);
#pragma unroll
        for (int i = 0; i < 4; ++i)
            gload16(bSrc + kt + (size_t)i*8*K, bDst + i*1024);
        __syncthreads();

#pragma unroll
        for (int kk = 0; kk < 2; ++kk) {
            bf16x8 af[4], bfr[4];
#pragma unroll
            for (int m = 0; m < 4; ++m) {
                int row  = wm*64 + m*16 + cl;
                int slot = ((kk<<2) + hi) ^ (row & 7);
                af[m] = *(const bf16x8*)((const char*)As + row*128 + slot*16);
            }
#pragma unroll
            for (int n = 0; n < 4; ++n) {
                int row  = wn*64 + n*16 + cl;
                int slot = ((kk<<2) + hi) ^ (row & 7);
                bfr[n] = *(const bf16x8*)((const char*)Bs + row*128 + slot*16);
            }
#pragma unroll
            for (int m = 0; m < 4; ++m)
#pragma unroll
                for (int n = 0; n < 4; ++n)
                    acc[m][n] = __builtin_amdgcn_mfma_f32_16x16x32_bf16(af[m], bfr[n], acc[m][n], 0, 0, 0);
        }
    }

    const int rowBase = m0 + wm*64;
    const int colBase = n0 + wn*64;
#pragma unroll
    for (int n = 0; n < 4; ++n) {
        const int col = colBase + n*16 + cl;
        const float bv = bias[col];
#pragma unroll
        for (int m = 0; m < 4; ++m) {
#pragma unroll
            for (int i = 0; i < 4; ++i) {
                const int row = rowBase + m*16 + hi*4 + i;
                float v = acc[m][n][i] + bv;
                if constexpr (EPI == 0) {
                    outb[(size_t)row*N + col] = __float2bfloat16(v);
                } else if constexpr (EPI == 1) {
                    float g = 0.5f * v * (1.0f + erff(v * 0.70710678118f));
                    outb[(size_t)row*N + col] = __float2bfloat16(g);
                } else {
                    const size_t ix = (size_t)row*N + col;
                    outf[ix] += v;
                }
            }
        }
    }
    (void)M;
}

// ---------------- flash attention (fp32 VALU), 64 q-rows per block ----------------
__global__ __launch_bounds__(256)
void attn_kernel(const __hip_bfloat16* __restrict__ qkvb, __hip_bfloat16* __restrict__ attno)
{
    __shared__ unsigned short qs[64][72];  // bf16 q tile
    __shared__ float ks[64][68];
    __shared__ float vs[64][68];
    __shared__ float ps[64][66];

    const unsigned short* qkv = (const unsigned short*)qkvb;
    const int nwg = gridDim.x, bid = blockIdx.x, chunk = nwg >> 3;
    const int swz = (bid & 7) * chunk + (bid >> 3);
    const int bh = swz >> 4, qb = swz & 15;
    const int b = bh / H_, h = bh % H_;
    const int s0 = qb * 64;
    const int tid = threadIdx.x;
    const size_t browq = (size_t)(b*S_ + s0);

    for (int i = tid; i < 4096; i += 256) {
        int rr = i >> 6, d = i & 63;
        qs[rr][d] = qkv[(browq + rr)*2304 + h*64 + d];
    }

    const int r = tid >> 2, cg = tid & 3;
    float m_r = -1e30f, l_r = 0.f;
    float o[16];
#pragma unroll
    for (int j = 0; j < 16; ++j) o[j] = 0.f;

    for (int t = 0; t < 16; ++t) {
        __syncthreads();
        for (int i = tid; i < 4096; i += 256) {
            int rr = i >> 6, d = i & 63;
            size_t base = ((size_t)(b*S_ + t*64 + rr))*2304 + h*64 + d;
            ks[rr][d] = bf2f(qkv[base + 768]);
            vs[rr][d] = bf2f(qkv[base + 1536]);
        }
        __syncthreads();

        float sc[16];
#pragma unroll
        for (int jj = 0; jj < 16; ++jj) sc[jj] = 0.f;
        for (int d4 = 0; d4 < 16; ++d4) {
            ushort4 qu = *(const ushort4*)&qs[r][d4*4];
            float q0 = bf2f(qu.x), q1 = bf2f(qu.y), q2 = bf2f(qu.z), q3 = bf2f(qu.w);
#pragma unroll
            for (int jj = 0; jj < 16; ++jj) {
                float4 kv = *(const float4*)&ks[jj*4 + cg][d4*4];
                sc[jj] += q0*kv.x + q1*kv.y + q2*kv.z + q3*kv.w;
            }
        }
        float mt = -1e30f;
#pragma unroll
        for (int jj = 0; jj < 16; ++jj) { sc[jj] *= 0.125f; mt = fmaxf(mt, sc[jj]); }
        mt = fmaxf(mt, __shfl_xor(mt, 1));
        mt = fmaxf(mt, __shfl_xor(mt, 2));
        const float mnew = fmaxf(m_r, mt);
        const float corr = __expf(m_r - mnew);
        float psum = 0.f;
#pragma unroll
        for (int jj = 0; jj < 16; ++jj) {
            float e = __expf(sc[jj] - mnew);
            ps[r][jj*4 + cg] = e;
            psum += e;
        }
        psum += __shfl_xor(psum, 1);
        psum += __shfl_xor(psum, 2);
        l_r = l_r * corr + psum;
        m_r = mnew;
#pragma unroll
        for (int j = 0; j < 16; ++j) o[j] *= corr;
        __syncthreads();
        for (int c = 0; c < 64; ++c) {
            float p = ps[r][c];
#pragma unroll
            for (int j4 = 0; j4 < 4; ++j4) {
                float4 vv = *(const float4*)&vs[c][cg*16 + j4*4];
                o[j4*4+0] += p*vv.x; o[j4*4+1] += p*vv.y;
                o[j4*4+2] += p*vv.z; o[j4*4+3] += p*vv.w;
            }
        }
    }
    const float inv = 1.f / l_r;
    unsigned short* op = (unsigned short*)attno + (browq + r)*768 + h*64 + cg*16;
#pragma unroll
    for (int j4 = 0; j4 < 4; ++j4) {
        ushort4 pk;
        pk.x = f2bf_bits(o[j4*4+0]*inv);
        pk.y = f2bf_bits(o[j4*4+1]*inv);
        pk.z = f2bf_bits(o[j4*4+2]*inv);
        pk.w = f2bf_bits(o[j4*4+3]*inv);
        *(ushort4*)(op + j4*4) = pk;
    }
}

// ---------------- classifier: out[b][n] = x[b*S,:] . Wc[:,n] + bc[n] ----------------
__global__ __launch_bounds__(256)
void cls_kernel(const float* __restrict__ x, const float* __restrict__ Wc,
                const float* __restrict__ bc, float* __restrict__ out)
{
    const int b = blockIdx.x;
    const float* xr = x + (size_t)b * S_ * D_;
    float a0 = 0.f, a1 = 0.f;
    for (int d = threadIdx.x; d < 768; d += 256) {
        float xv = xr[d];
        a0 += xv * Wc[d*2+0];
        a1 += xv * Wc[d*2+1];
    }
#pragma unroll
    for (int off = 32; off > 0; off >>= 1) { a0 += __shfl_xor(a0, off); a1 += __shfl_xor(a1, off); }
    __shared__ float r0[4], r1[4];
    const int w = threadIdx.x >> 6;
    if ((threadIdx.x & 63) == 0) { r0[w] = a0; r1[w] = a1; }
    __syncthreads();
    if (threadIdx.x == 0) {
        out[b*2+0] = r0[0]+r0[1]+r0[2]+r0[3] + bc[0];
        out[b*2+1] = r1[0]+r1[1]+r1[2]+r1[3] + bc[1];
    }
}

// ---------------- launch ----------------
extern "C" void kernel_launch(void* const* d_in, const int* in_sizes, int n_in,
                              void* d_out, int out_size, void* d_ws, size_t ws_size,
                              hipStream_t stream)
{
    const int*   tokens  = (const int*)  d_in[0];
    const float* tok_emb = (const float*)d_in[1];
    const float* pos_emb = (const float*)d_in[2];
    const float* e_s     = (const float*)d_in[3];
    const float* e_b     = (const float*)d_in[4];
    const float* Wq      = (const float*)d_in[5];
    const float* bq      = (const float*)d_in[6];
    const float* Wk      = (const float*)d_in[7];
    const float* bk      = (const float*)d_in[8];
    const float* Wv      = (const float*)d_in[9];
    const float* bv      = (const float*)d_in[10];
    const float* Wo      = (const float*)d_in[11];
    const float* bo      = (const float*)d_in[12];
    const float* l1s     = (const float*)d_in[13];
    const float* l1b     = (const float*)d_in[14];
    const float* l2s     = (const float*)d_in[15];
    const float* l2b     = (const float*)d_in[16];
    const float* W1      = (const float*)d_in[17];
    const float* b1      = (const float*)d_in[18];
    const float* W2      = (const float*)d_in[19];
    const float* b2      = (const float*)d_in[20];
    const float* Wc      = (const float*)d_in[21];
    const float* bc      = (const float*)d_in[22];
    (void)in_sizes; (void)n_in; (void)out_size;

    if (ws_size < 102346752) return;   // need ~102.4 MB

    char* ws = (char*)d_ws;
    __hip_bfloat16* wbuf = (__hip_bfloat16*)(ws + 0);          // 14,155,776 B (per-layer bf16 W^T)
    float*          bqkv = (float*)(ws + 14155776);            //    110,592 B
    float*          x    = (float*)(ws + 14266368);            // 25,165,824 B (fp32 residual)
    __hip_bfloat16* xn   = (__hip_bfloat16*)(ws + 39432192);   // 12,582,912 B
    __hip_bfloat16* qkv  = (__hip_bfloat16*)(ws + 52015104);   // 37,748,736 B
    __hip_bfloat16* att  = (__hip_bfloat16*)(ws + 89763840);   // 12,582,912 B  (end 102,346,752)
    __hip_bfloat16* hbuf = qkv;                                // aliases qkv+att (50,331,648 B)

    __hip_bfloat16* wqkv_t = wbuf;
    __hip_bfloat16* wo_t   = wbuf + 1769472;
    __hip_bfloat16* w1_t   = wbuf + 2359296;
    __hip_bfloat16* w2_t   = wbuf + 4718592;

    prep_bqkv_kernel<<<108, 256, 0, stream>>>(bq, bk, bv, bqkv);
    embed_ln_kernel<<<2048, 256, 0, stream>>>(tokens, tok_emb, pos_emb, e_s, e_b, x);

    for (int l = 0; l < L_; ++l) {
        prep_layer_kernel<<<1728, 256, 0, stream>>>(Wq, Wk, Wv, Wo, W1, W2, l, wbuf);
        ln_kernel<<<2048, 256, 0, stream>>>(x, l1s + l*768, l1b + l*768, xn);
        gemm_kernel<0><<<1152, 256, 0, stream>>>(xn, wqkv_t, bqkv + l*2304, qkv, nullptr, NTOK, 2304, 768, 18);
        attn_kernel<<<1536, 256, 0, stream>>>(qkv, att);
        gemm_kernel<2><<<384, 256, 0, stream>>>(att, wo_t, bo + l*768, nullptr, x, NTOK, 768, 768, 6);
        ln_kernel<<<2048, 256, 0, stream>>>(x, l2s + l*768, l2b + l*768, xn);
        gemm_kernel<1><<<1536, 256, 0, stream>>>(xn, w1_t, b1 + l*3072, hbuf, nullptr, NTOK, 3072, 768, 24);
        gemm_kernel<2><<<384, 256, 0, stream>>>(hbuf, w2_t, b2 + l*768, nullptr, x, NTOK, 768, 3072, 6);
    }
    cls_kernel<<<8, 256, 0, stream>>>(x, Wc, bc, (float*)d_out);
}

// Round 2
// 3903.058 us; speedup vs baseline: 2.5373x; 2.5373x over previous
//
#include <hip/hip_runtime.h>
#include <hip/hip_bf16.h>
#include <math.h>

// ---------------- constants ----------------
#define B_   8
#define S_   1024
#define D_   768
#define H_   12
#define HD_  64
#define L_   12
#define F_   3072
#define NTOK 8192   // B_*S_

typedef __bf16 bf16x8 __attribute__((ext_vector_type(8)));
typedef float  f32x4  __attribute__((ext_vector_type(4)));
typedef unsigned short u16;
typedef u16 u16x8 __attribute__((ext_vector_type(8)));

static __device__ __forceinline__ unsigned short f2bf_bits(float f) {
    __hip_bfloat16 h = __float2bfloat16(f);
    return __builtin_bit_cast(unsigned short, h);
}
static __device__ __forceinline__ float bf2f(unsigned short u) {
    unsigned int t = ((unsigned int)u) << 16;
    return __builtin_bit_cast(float, t);
}
static __device__ __forceinline__ void gload16(const void* g, void* l) {
    __builtin_amdgcn_global_load_lds(
        (__attribute__((address_space(1))) void*)g,
        (__attribute__((address_space(3))) void*)l, 16, 0, 0);
}

// ---------------- weight prep: fp32 [R][C] -> bf16 transposed [C][R] ----------------
__global__ __launch_bounds__(256)
void prep_layer_kernel(const float* __restrict__ Wq, const float* __restrict__ Wk,
                       const float* __restrict__ Wv, const float* __restrict__ Wo,
                       const float* __restrict__ W1, const float* __restrict__ W2,
                       int l, __hip_bfloat16* __restrict__ wbuf)
{
    const int id = blockIdx.x;   // 0..1727
    const float* src; __hip_bfloat16* dst;
    int R, C, r0, c0;
    if (id < 432) {                       // q/k/v heads: src [768][64] per (which,h)
        int dtile = id % 12, t = id / 12; // t = which*12 + h
        int which = t / 12, h = t % 12;
        src = (which == 0 ? Wq : which == 1 ? Wk : Wv) + (size_t)(l*12 + h) * 768 * 64;
        dst = wbuf + (size_t)(which*768 + h*64) * 768;
        R = 768; C = 64; r0 = dtile * 64; c0 = 0;
    } else if (id < 576) {                // Wo: [768][768]
        int t = id - 432;
        src = Wo + (size_t)l * 768 * 768;
        dst = wbuf + 1769472;
        R = 768; C = 768; r0 = (t / 12) * 64; c0 = (t % 12) * 64;
    } else if (id < 1152) {               // W1: [768][3072]
        int t = id - 576;
        src = W1 + (size_t)l * 768 * 3072;
        dst = wbuf + 2359296;
        R = 768; C = 3072; r0 = (t % 12) * 64; c0 = (t / 12) * 64;
    } else {                              // W2: [3072][768]
        int t = id - 1152;
        src = W2 + (size_t)l * 3072 * 768;
        dst = wbuf + 4718592;
        R = 3072; C = 768; r0 = (t / 12) * 64; c0 = (t % 12) * 64;
    }
    __shared__ float tile[64][65];
    for (int i = threadIdx.x; i < 4096; i += 256) {
        int rr = i >> 6, cc = i & 63;
        tile[rr][cc] = src[(size_t)(r0 + rr) * C + (c0 + cc)];
    }
    __syncthreads();
    for (int i = threadIdx.x; i < 4096; i += 256) {
        int cc = i >> 6, rr = i & 63;
        dst[(size_t)(c0 + cc) * R + (r0 + rr)] = __float2bfloat16(tile[rr][cc]);
    }
}

__global__ __launch_bounds__(256)
void prep_bqkv_kernel(const float* __restrict__ bq, const float* __restrict__ bk,
                      const float* __restrict__ bv, float* __restrict__ bqkv)
{
    int i = blockIdx.x * 256 + threadIdx.x;   // < 12*2304
    int l = i / 2304, c = i % 2304;
    int which = c / 768, hk = c % 768;
    const float* src = which == 0 ? bq : which == 1 ? bk : bv;
    bqkv[i] = src[l*768 + hk];
}

// ---------------- embedding + LN -> x (fp32) ----------------
__global__ __launch_bounds__(256)
void embed_ln_kernel(const int* __restrict__ tokens, const float* __restrict__ tok_emb,
                     const float* __restrict__ pos_emb, const float* __restrict__ gam,
                     const float* __restrict__ bet, float* __restrict__ x)
{
    const int row  = blockIdx.x*4 + (threadIdx.x >> 6);
    const int lane = threadIdx.x & 63;
    const int s    = row & (S_-1);
    const int tok  = tokens[row];
    const float* te = tok_emb + (size_t)tok * D_;
    const float* pe = pos_emb + (size_t)s   * D_;
    float v[12]; float s1 = 0.f, s2 = 0.f;
#pragma unroll
    for (int c = 0; c < 3; ++c) {
        const int base = c*256 + lane*4;
        float4 a = *(const float4*)(te + base);
        float4 p = *(const float4*)(pe + base);
        float t0 = a.x+p.x, t1 = a.y+p.y, t2 = a.z+p.z, t3 = a.w+p.w;
        v[c*4+0]=t0; v[c*4+1]=t1; v[c*4+2]=t2; v[c*4+3]=t3;
        s1 += t0+t1+t2+t3;
        s2 += t0*t0 + t1*t1 + t2*t2 + t3*t3;
    }
#pragma unroll
    for (int off = 32; off > 0; off >>= 1) { s1 += __shfl_xor(s1, off); s2 += __shfl_xor(s2, off); }
    const float mean = s1 * (1.f/768.f);
    const float rstd = rsqrtf(s2*(1.f/768.f) - mean*mean + 1e-5f);
    float* xr = x + (size_t)row * D_;
#pragma unroll
    for (int c = 0; c < 3; ++c) {
        const int base = c*256 + lane*4;
        float4 g = *(const float4*)(gam + base);
        float4 bb = *(const float4*)(bet + base);
        float4 o;
        o.x = (v[c*4+0]-mean)*rstd*g.x + bb.x;
        o.y = (v[c*4+1]-mean)*rstd*g.y + bb.y;
        o.z = (v[c*4+2]-mean)*rstd*g.z + bb.z;
        o.w = (v[c*4+3]-mean)*rstd*g.w + bb.w;
        *(float4*)(xr + base) = o;
    }
}

// ---------------- LN: x (fp32) -> xn (bf16) ----------------
__global__ __launch_bounds__(256)
void ln_kernel(const float* __restrict__ xin, const float* __restrict__ gam,
               const float* __restrict__ bet, __hip_bfloat16* __restrict__ out)
{
    const int row  = blockIdx.x*4 + (threadIdx.x >> 6);
    const int lane = threadIdx.x & 63;
    const float* xr = xin + (size_t)row * D_;
    float v[12]; float s1 = 0.f, s2 = 0.f;
#pragma unroll
    for (int c = 0; c < 3; ++c) {
        float4 t = *(const float4*)(xr + c*256 + lane*4);
        v[c*4+0]=t.x; v[c*4+1]=t.y; v[c*4+2]=t.z; v[c*4+3]=t.w;
        s1 += t.x+t.y+t.z+t.w;
        s2 += t.x*t.x + t.y*t.y + t.z*t.z + t.w*t.w;
    }
#pragma unroll
    for (int off = 32; off > 0; off >>= 1) { s1 += __shfl_xor(s1, off); s2 += __shfl_xor(s2, off); }
    const float mean = s1 * (1.f/768.f);
    const float rstd = rsqrtf(s2*(1.f/768.f) - mean*mean + 1e-5f);
    unsigned short* op = (unsigned short*)out + (size_t)row * D_;
#pragma unroll
    for (int c = 0; c < 3; ++c) {
        const int base = c*256 + lane*4;
        float4 g = *(const float4*)(gam + base);
        float4 bb = *(const float4*)(bet + base);
        ushort4 pk;
        pk.x = f2bf_bits((v[c*4+0]-mean)*rstd*g.x + bb.x);
        pk.y = f2bf_bits((v[c*4+1]-mean)*rstd*g.y + bb.y);
        pk.z = f2bf_bits((v[c*4+2]-mean)*rstd*g.z + bb.z);
        pk.w = f2bf_bits((v[c*4+3]-mean)*rstd*g.w + bb.w);
        *(ushort4*)(op + base) = pk;
    }
}

// ---------------- GEMM: C[M,N] = A[M,K](bf16) * Bt[N,K](bf16)^T + bias ----------------
template<int EPI>
__global__ __launch_bounds__(256)
void gemm_kernel(const __hip_bfloat16* __restrict__ A,
                 const __hip_bfloat16* __restrict__ Bt,
                 const float* __restrict__ bias,
                 __hip_bfloat16* __restrict__ outb,
                 float* __restrict__ outf,
                 int M, int N, int K, int nTiles)
{
    __shared__ __hip_bfloat16 As[128*64];
    __shared__ __hip_bfloat16 Bs[128*64];

    const int tid  = threadIdx.x;
    const int lane = tid & 63;
    const int wid  = tid >> 6;

    const int nwg   = gridDim.x;
    const int chunk = nwg >> 3;
    const int bid   = blockIdx.x;
    const int swz   = (bid & 7) * chunk + (bid >> 3);
    const int m0 = (swz / nTiles) * 128;
    const int n0 = (swz % nTiles) * 128;

    const int srow = wid*32 + (lane >> 3);
    const int scol = ((lane & 7) ^ (srow & 7)) * 8;
    const __hip_bfloat16* aSrc = A  + (size_t)(m0 + srow) * K + scol;
    const __hip_bfloat16* bSrc = Bt + (size_t)(n0 + srow) * K + scol;
    char* aDst = (char*)As + wid*4096 + lane*16;
    char* bDst = (char*)Bs + wid*4096 + lane*16;

    f32x4 acc[4][4] = {};
    const int wm = wid >> 1, wn = wid & 1;
    const int cl = lane & 15, hi = lane >> 4;

    for (int kt = 0; kt < K; kt += 64) {
        __syncthreads();
#pragma unroll
        for (int i = 0; i < 4; ++i)
            gload16(aSrc + kt + (size_t)i*8*K, aDst + i*1024);
#pragma unroll
        for (int i = 0; i < 4; ++i)
            gload16(bSrc + kt + (size_t)i*8*K, bDst + i*1024);
        __syncthreads();

#pragma unroll
        for (int kk = 0; kk < 2; ++kk) {
            bf16x8 af[4], bfr[4];
#pragma unroll
            for (int m = 0; m < 4; ++m) {
                int row  = wm*64 + m*16 + cl;
                int slot = ((kk<<2) + hi) ^ (row & 7);
                af[m] = *(const bf16x8*)((const char*)As + row*128 + slot*16);
            }
#pragma unroll
            for (int n = 0; n < 4; ++n) {
                int row  = wn*64 + n*16 + cl;
                int slot = ((kk<<2) + hi) ^ (row & 7);
                bfr[n] = *(const bf16x8*)((const char*)Bs + row*128 + slot*16);
            }
#pragma unroll
            for (int m = 0; m < 4; ++m)
#pragma unroll
                for (int n = 0; n < 4; ++n)
                    acc[m][n] = __builtin_amdgcn_mfma_f32_16x16x32_bf16(af[m], bfr[n], acc[m][n], 0, 0, 0);
        }
    }

    const int rowBase = m0 + wm*64;
    const int colBase = n0 + wn*64;
#pragma unroll
    for (int n = 0; n < 4; ++n) {
        const int col = colBase + n*16 + cl;
        const float bv = bias[col];
#pragma unroll
        for (int m = 0; m < 4; ++m) {
#pragma unroll
            for (int i = 0; i < 4; ++i) {
                const int row = rowBase + m*16 + hi*4 + i;
                float v = acc[m][n][i] + bv;
                if constexpr (EPI == 0) {
                    outb[(size_t)row*N + col] = __float2bfloat16(v);
                } else if constexpr (EPI == 1) {
                    float g = 0.5f * v * (1.0f + erff(v * 0.70710678118f));
                    outb[(size_t)row*N + col] = __float2bfloat16(g);
                } else {
                    const size_t ix = (size_t)row*N + col;
                    outf[ix] += v;
                }
            }
        }
    }
    (void)M;
}

// ---------------- flash attention, MFMA bf16 ----------------
// Block = 4 waves, 64 q rows of one (b,h). 16 K/V tiles of 64.
// Fragment conventions identical to gemm_kernel (verified): operands loaded as
// row=cl, k=(kk*4+hi)*8+j; mfma(X,Y) -> out row(hi*4+i)=X.row, col(cl)=Y.row.
__global__ __launch_bounds__(256)
void attn_kernel(const __hip_bfloat16* __restrict__ qkvb, __hip_bfloat16* __restrict__ attno)
{
    __shared__ __align__(16) char Ks[8192];   // K tile: [t 64][d 64] bf16, slot^=(t&7)
    __shared__ __align__(16) char Vt[8192];   // V^T tile: [d 64][t 64] bf16, slot^=(d&7)
    __shared__ __align__(16) char Ps[8192];   // P per wave: [q 16][t 64] bf16, slot^=(q&7)

    const u16* qkv = (const u16*)qkvb;
    const int nwg = gridDim.x, bid = blockIdx.x, chunk = nwg >> 3;
    const int swz = (bid & 7) * chunk + (bid >> 3);
    const int bh = swz >> 4, qb = swz & 15;
    const int b = bh / H_, h = bh % H_;
    const int tid = threadIdx.x;
    const int lane = tid & 63, wid = tid >> 6;
    const int cl = lane & 15, hi = lane >> 4;
    const size_t browq  = (size_t)(b*S_ + qb*64);
    const size_t browkv = (size_t)(b*S_);

    // Q fragments: row = wid*16 + cl, k=d
    bf16x8 qf[2];
    {
        const u16* qp = qkv + (browq + wid*16 + cl)*2304 + h*64;
        qf[0] = *(const bf16x8*)(qp + hi*8);
        qf[1] = *(const bf16x8*)(qp + 32 + hi*8);
    }

    f32x4 acc_o[4] = {};
    float m_run[4], l_run[4];
#pragma unroll
    for (int i = 0; i < 4; ++i) { m_run[i] = -1e30f; l_run[i] = 0.f; }

    const int krow_local = lane >> 3;          // 0..7
    const int ksrc_col = (((lane & 7) ^ krow_local) * 8);
    char* kdst = Ks + wid*2048 + lane*16;
    const int vd = lane;                       // d for V transpose
    char* pbase = Ps + wid*2048;

    for (int t = 0; t < 16; ++t) {
        const size_t trow = browkv + t*64;
        __syncthreads();
        // stage K tile (16 rows/wave, 2 gload rounds of 8 rows)
#pragma unroll
        for (int i = 0; i < 2; ++i) {
            const u16* src = qkv + (trow + wid*16 + i*8 + krow_local)*2304 + h*64 + 768 + ksrc_col;
            gload16(src, kdst + i*1024);
        }
        // stage V transposed: lane owns column d=vd, t range [wid*16, wid*16+16)
        {
            const u16* vbase = qkv + (trow + wid*16)*2304 + h*64 + 1536 + vd;
#pragma unroll
            for (int g = 0; g < 2; ++g) {
                u16x8 pack;
#pragma unroll
                for (int j = 0; j < 8; ++j)
                    pack[j] = vbase[(size_t)(g*8 + j)*2304];
                const int slot = (wid*2 + g) ^ (vd & 7);
                *(u16x8*)(Vt + vd*128 + slot*16) = pack;
            }
        }
        __syncthreads();

        // QK^T -> sc[n] (q=hi*4+i, t=n*16+cl)
        f32x4 sc[4] = {};
#pragma unroll
        for (int kk = 0; kk < 2; ++kk) {
            bf16x8 kf[4];
#pragma unroll
            for (int n = 0; n < 4; ++n) {
                const int row = n*16 + cl;
                const int slot = (kk*4 + hi) ^ (cl & 7);
                kf[n] = *(const bf16x8*)(Ks + row*128 + slot*16);
            }
#pragma unroll
            for (int n = 0; n < 4; ++n)
                sc[n] = __builtin_amdgcn_mfma_f32_16x16x32_bf16(qf[kk], kf[n], sc[n], 0, 0, 0);
        }

        // online softmax (per q-row = (hi,i); row spans 16 lanes of same hi)
        float mnew[4], corr[4];
#pragma unroll
        for (int n = 0; n < 4; ++n)
#pragma unroll
            for (int i = 0; i < 4; ++i)
                sc[n][i] *= 0.125f;
#pragma unroll
        for (int i = 0; i < 4; ++i) {
            float mt = fmaxf(fmaxf(sc[0][i], sc[1][i]), fmaxf(sc[2][i], sc[3][i]));
            mt = fmaxf(mt, __shfl_xor(mt, 1));
            mt = fmaxf(mt, __shfl_xor(mt, 2));
            mt = fmaxf(mt, __shfl_xor(mt, 4));
            mt = fmaxf(mt, __shfl_xor(mt, 8));
            mnew[i] = fmaxf(m_run[i], mt);
            corr[i] = __expf(m_run[i] - mnew[i]);
            m_run[i] = mnew[i];
        }
        float psum[4] = {0.f, 0.f, 0.f, 0.f};
#pragma unroll
        for (int n = 0; n < 4; ++n) {
#pragma unroll
            for (int i = 0; i < 4; ++i) {
                const float e = __expf(sc[n][i] - mnew[i]);
                psum[i] += e;
                const int q = hi*4 + i;
                const int slot = (n*2 + (cl >> 3)) ^ (q & 7);
                *(u16*)(pbase + q*128 + slot*16 + (cl & 7)*2) = f2bf_bits(e);
            }
        }
#pragma unroll
        for (int i = 0; i < 4; ++i) {
            float ps = psum[i];
            ps += __shfl_xor(ps, 1);
            ps += __shfl_xor(ps, 2);
            ps += __shfl_xor(ps, 4);
            ps += __shfl_xor(ps, 8);
            l_run[i] = l_run[i]*corr[i] + ps;
        }
#pragma unroll
        for (int nd = 0; nd < 4; ++nd)
#pragma unroll
            for (int i = 0; i < 4; ++i)
                acc_o[nd][i] *= corr[i];

        // wave-local visibility of P writes (per-wave region; no block barrier needed)
        asm volatile("s_waitcnt lgkmcnt(0)" ::: "memory");
        __builtin_amdgcn_sched_barrier(0);

        // PV: acc_o[nd] += P(frag A) * Vt(frag B)
#pragma unroll
        for (int kk = 0; kk < 2; ++kk) {
            const bf16x8 pf = *(const bf16x8*)(pbase + cl*128 + (((kk*4 + hi) ^ (cl & 7)) << 4));
            bf16x8 vf[4];
#pragma unroll
            for (int nd = 0; nd < 4; ++nd) {
                const int d = nd*16 + cl;
                const int slot = (kk*4 + hi) ^ (cl & 7);
                vf[nd] = *(const bf16x8*)(Vt + d*128 + slot*16);
            }
#pragma unroll
            for (int nd = 0; nd < 4; ++nd)
                acc_o[nd] = __builtin_amdgcn_mfma_f32_16x16x32_bf16(pf, vf[nd], acc_o[nd], 0, 0, 0);
        }
    }

    // epilogue: O /= l, store bf16
    u16* op = (u16*)attno;
#pragma unroll
    for (int i = 0; i < 4; ++i) {
        const float inv = 1.f / l_run[i];
        const size_t row = browq + wid*16 + hi*4 + i;
#pragma unroll
        for (int nd = 0; nd < 4; ++nd)
            op[row*768 + h*64 + nd*16 + cl] = f2bf_bits(acc_o[nd][i] * inv);
    }
}

// ---------------- classifier ----------------
__global__ __launch_bounds__(256)
void cls_kernel(const float* __restrict__ x, const float* __restrict__ Wc,
                const float* __restrict__ bc, float* __restrict__ out)
{
    const int b = blockIdx.x;
    const float* xr = x + (size_t)b * S_ * D_;
    float a0 = 0.f, a1 = 0.f;
    for (int d = threadIdx.x; d < 768; d += 256) {
        float xv = xr[d];
        a0 += xv * Wc[d*2+0];
        a1 += xv * Wc[d*2+1];
    }
#pragma unroll
    for (int off = 32; off > 0; off >>= 1) { a0 += __shfl_xor(a0, off); a1 += __shfl_xor(a1, off); }
    __shared__ float r0[4], r1[4];
    const int w = threadIdx.x >> 6;
    if ((threadIdx.x & 63) == 0) { r0[w] = a0; r1[w] = a1; }
    __syncthreads();
    if (threadIdx.x == 0) {
        out[b*2+0] = r0[0]+r0[1]+r0[2]+r0[3] + bc[0];
        out[b*2+1] = r1[0]+r1[1]+r1[2]+r1[3] + bc[1];
    }
}

// ---------------- launch ----------------
extern "C" void kernel_launch(void* const* d_in, const int* in_sizes, int n_in,
                              void* d_out, int out_size, void* d_ws, size_t ws_size,
                              hipStream_t stream)
{
    const int*   tokens  = (const int*)  d_in[0];
    const float* tok_emb = (const float*)d_in[1];
    const float* pos_emb = (const float*)d_in[2];
    const float* e_s     = (const float*)d_in[3];
    const float* e_b     = (const float*)d_in[4];
    const float* Wq      = (const float*)d_in[5];
    const float* bq      = (const float*)d_in[6];
    const float* Wk      = (const float*)d_in[7];
    const float* bk      = (const float*)d_in[8];
    const float* Wv      = (const float*)d_in[9];
    const float* bv      = (const float*)d_in[10];
    const float* Wo      = (const float*)d_in[11];
    const float* bo      = (const float*)d_in[12];
    const float* l1s     = (const float*)d_in[13];
    const float* l1b     = (const float*)d_in[14];
    const float* l2s     = (const float*)d_in[15];
    const float* l2b     = (const float*)d_in[16];
    const float* W1      = (const float*)d_in[17];
    const float* b1      = (const float*)d_in[18];
    const float* W2      = (const float*)d_in[19];
    const float* b2      = (const float*)d_in[20];
    const float* Wc      = (const float*)d_in[21];
    const float* bc      = (const float*)d_in[22];
    (void)in_sizes; (void)n_in; (void)out_size;

    if (ws_size < 102346752) return;   // need ~102.4 MB

    char* ws = (char*)d_ws;
    __hip_bfloat16* wbuf = (__hip_bfloat16*)(ws + 0);          // 14,155,776 B
    float*          bqkv = (float*)(ws + 14155776);            //    110,592 B
    float*          x    = (float*)(ws + 14266368);            // 25,165,824 B
    __hip_bfloat16* xn   = (__hip_bfloat16*)(ws + 39432192);   // 12,582,912 B
    __hip_bfloat16* qkv  = (__hip_bfloat16*)(ws + 52015104);   // 37,748,736 B
    __hip_bfloat16* att  = (__hip_bfloat16*)(ws + 89763840);   // 12,582,912 B
    __hip_bfloat16* hbuf = qkv;                                // aliases qkv+att

    __hip_bfloat16* wqkv_t = wbuf;
    __hip_bfloat16* wo_t   = wbuf + 1769472;
    __hip_bfloat16* w1_t   = wbuf + 2359296;
    __hip_bfloat16* w2_t   = wbuf + 4718592;

    prep_bqkv_kernel<<<108, 256, 0, stream>>>(bq, bk, bv, bqkv);
    embed_ln_kernel<<<2048, 256, 0, stream>>>(tokens, tok_emb, pos_emb, e_s, e_b, x);

    for (int l = 0; l < L_; ++l) {
        prep_layer_kernel<<<1728, 256, 0, stream>>>(Wq, Wk, Wv, Wo, W1, W2, l, wbuf);
        ln_kernel<<<2048, 256, 0, stream>>>(x, l1s + l*768, l1b + l*768, xn);
        gemm_kernel<0><<<1152, 256, 0, stream>>>(xn, wqkv_t, bqkv + l*2304, qkv, nullptr, NTOK, 2304, 768, 18);
        attn_kernel<<<1536, 256, 0, stream>>>(qkv, att);
        gemm_kernel<2><<<384, 256, 0, stream>>>(att, wo_t, bo + l*768, nullptr, x, NTOK, 768, 768, 6);
        ln_kernel<<<2048, 256, 0, stream>>>(x, l2s + l*768, l2b + l*768, xn);
        gemm_kernel<1><<<1536, 256, 0, stream>>>(xn, w1_t, b1 + l*3072, hbuf, nullptr, NTOK, 3072, 768, 24);
        gemm_kernel<2><<<384, 256, 0, stream>>>(hbuf, w2_t, b2 + l*768, nullptr, x, NTOK, 768, 3072, 6);
    }
    cls_kernel<<<8, 256, 0, stream>>>(x, Wc, bc, (float*)d_out);
}

// Round 3
// 3598.100 us; speedup vs baseline: 2.7524x; 1.0848x over previous
//
#include <hip/hip_runtime.h>
#include <hip/hip_bf16.h>
#include <math.h>

// ---------------- constants ----------------
#define B_   8
#define S_   1024
#define D_   768
#define H_   12
#define HD_  64
#define L_   12
#define F_   3072
#define NTOK 8192   // B_*S_

typedef __bf16 bf16x8 __attribute__((ext_vector_type(8)));
typedef float  f32x4  __attribute__((ext_vector_type(4)));
typedef unsigned short u16;

static __device__ __forceinline__ unsigned short f2bf_bits(float f) {
    __hip_bfloat16 h = __float2bfloat16(f);
    return __builtin_bit_cast(unsigned short, h);
}
static __device__ __forceinline__ float bf2f(unsigned short u) {
    unsigned int t = ((unsigned int)u) << 16;
    return __builtin_bit_cast(float, t);
}
static __device__ __forceinline__ void gload16(const void* g, void* l) {
    __builtin_amdgcn_global_load_lds(
        (__attribute__((address_space(1))) void*)g,
        (__attribute__((address_space(3))) void*)l, 16, 0, 0);
}

// ---------------- weight prep: fp32 [R][C] -> bf16 transposed [C][R] ----------------
__global__ __launch_bounds__(256)
void prep_layer_kernel(const float* __restrict__ Wq, const float* __restrict__ Wk,
                       const float* __restrict__ Wv, const float* __restrict__ Wo,
                       const float* __restrict__ W1, const float* __restrict__ W2,
                       int l, __hip_bfloat16* __restrict__ wbuf)
{
    const int id = blockIdx.x;   // 0..1727
    const float* src; __hip_bfloat16* dst;
    int R, C, r0, c0;
    if (id < 432) {                       // q/k/v heads: src [768][64] per (which,h)
        int dtile = id % 12, t = id / 12; // t = which*12 + h
        int which = t / 12, h = t % 12;
        src = (which == 0 ? Wq : which == 1 ? Wk : Wv) + (size_t)(l*12 + h) * 768 * 64;
        dst = wbuf + (size_t)(which*768 + h*64) * 768;
        R = 768; C = 64; r0 = dtile * 64; c0 = 0;
    } else if (id < 576) {                // Wo: [768][768]
        int t = id - 432;
        src = Wo + (size_t)l * 768 * 768;
        dst = wbuf + 1769472;
        R = 768; C = 768; r0 = (t / 12) * 64; c0 = (t % 12) * 64;
    } else if (id < 1152) {               // W1: [768][3072]
        int t = id - 576;
        src = W1 + (size_t)l * 768 * 3072;
        dst = wbuf + 2359296;
        R = 768; C = 3072; r0 = (t % 12) * 64; c0 = (t / 12) * 64;
    } else {                              // W2: [3072][768]
        int t = id - 1152;
        src = W2 + (size_t)l * 3072 * 768;
        dst = wbuf + 4718592;
        R = 3072; C = 768; r0 = (t / 12) * 64; c0 = (t % 12) * 64;
    }
    __shared__ float tile[64][65];
    for (int i = threadIdx.x; i < 4096; i += 256) {
        int rr = i >> 6, cc = i & 63;
        tile[rr][cc] = src[(size_t)(r0 + rr) * C + (c0 + cc)];
    }
    __syncthreads();
    for (int i = threadIdx.x; i < 4096; i += 256) {
        int cc = i >> 6, rr = i & 63;
        dst[(size_t)(c0 + cc) * R + (r0 + rr)] = __float2bfloat16(tile[rr][cc]);
    }
}

__global__ __launch_bounds__(256)
void prep_bqkv_kernel(const float* __restrict__ bq, const float* __restrict__ bk,
                      const float* __restrict__ bv, float* __restrict__ bqkv)
{
    int i = blockIdx.x * 256 + threadIdx.x;   // < 12*2304
    int l = i / 2304, c = i % 2304;
    int which = c / 768, hk = c % 768;
    const float* src = which == 0 ? bq : which == 1 ? bk : bv;
    bqkv[i] = src[l*768 + hk];
}

// ---------------- embedding + LN -> x (fp32) ----------------
__global__ __launch_bounds__(256)
void embed_ln_kernel(const int* __restrict__ tokens, const float* __restrict__ tok_emb,
                     const float* __restrict__ pos_emb, const float* __restrict__ gam,
                     const float* __restrict__ bet, float* __restrict__ x)
{
    const int row  = blockIdx.x*4 + (threadIdx.x >> 6);
    const int lane = threadIdx.x & 63;
    const int s    = row & (S_-1);
    const int tok  = tokens[row];
    const float* te = tok_emb + (size_t)tok * D_;
    const float* pe = pos_emb + (size_t)s   * D_;
    float v[12]; float s1 = 0.f, s2 = 0.f;
#pragma unroll
    for (int c = 0; c < 3; ++c) {
        const int base = c*256 + lane*4;
        float4 a = *(const float4*)(te + base);
        float4 p = *(const float4*)(pe + base);
        float t0 = a.x+p.x, t1 = a.y+p.y, t2 = a.z+p.z, t3 = a.w+p.w;
        v[c*4+0]=t0; v[c*4+1]=t1; v[c*4+2]=t2; v[c*4+3]=t3;
        s1 += t0+t1+t2+t3;
        s2 += t0*t0 + t1*t1 + t2*t2 + t3*t3;
    }
#pragma unroll
    for (int off = 32; off > 0; off >>= 1) { s1 += __shfl_xor(s1, off); s2 += __shfl_xor(s2, off); }
    const float mean = s1 * (1.f/768.f);
    const float rstd = rsqrtf(s2*(1.f/768.f) - mean*mean + 1e-5f);
    float* xr = x + (size_t)row * D_;
#pragma unroll
    for (int c = 0; c < 3; ++c) {
        const int base = c*256 + lane*4;
        float4 g = *(const float4*)(gam + base);
        float4 bb = *(const float4*)(bet + base);
        float4 o;
        o.x = (v[c*4+0]-mean)*rstd*g.x + bb.x;
        o.y = (v[c*4+1]-mean)*rstd*g.y + bb.y;
        o.z = (v[c*4+2]-mean)*rstd*g.z + bb.z;
        o.w = (v[c*4+3]-mean)*rstd*g.w + bb.w;
        *(float4*)(xr + base) = o;
    }
}

// ---------------- LN: x (fp32) -> xn (bf16) ----------------
__global__ __launch_bounds__(256)
void ln_kernel(const float* __restrict__ xin, const float* __restrict__ gam,
               const float* __restrict__ bet, __hip_bfloat16* __restrict__ out)
{
    const int row  = blockIdx.x*4 + (threadIdx.x >> 6);
    const int lane = threadIdx.x & 63;
    const float* xr = xin + (size_t)row * D_;
    float v[12]; float s1 = 0.f, s2 = 0.f;
#pragma unroll
    for (int c = 0; c < 3; ++c) {
        float4 t = *(const float4*)(xr + c*256 + lane*4);
        v[c*4+0]=t.x; v[c*4+1]=t.y; v[c*4+2]=t.z; v[c*4+3]=t.w;
        s1 += t.x+t.y+t.z+t.w;
        s2 += t.x*t.x + t.y*t.y + t.z*t.z + t.w*t.w;
    }
#pragma unroll
    for (int off = 32; off > 0; off >>= 1) { s1 += __shfl_xor(s1, off); s2 += __shfl_xor(s2, off); }
    const float mean = s1 * (1.f/768.f);
    const float rstd = rsqrtf(s2*(1.f/768.f) - mean*mean + 1e-5f);
    unsigned short* op = (unsigned short*)out + (size_t)row * D_;
#pragma unroll
    for (int c = 0; c < 3; ++c) {
        const int base = c*256 + lane*4;
        float4 g = *(const float4*)(gam + base);
        float4 bb = *(const float4*)(bet + base);
        ushort4 pk;
        pk.x = f2bf_bits((v[c*4+0]-mean)*rstd*g.x + bb.x);
        pk.y = f2bf_bits((v[c*4+1]-mean)*rstd*g.y + bb.y);
        pk.z = f2bf_bits((v[c*4+2]-mean)*rstd*g.z + bb.z);
        pk.w = f2bf_bits((v[c*4+3]-mean)*rstd*g.w + bb.w);
        *(ushort4*)(op + base) = pk;
    }
}

// ---------------- GEMM: C[M,N] = A[M,K](bf16) * Bt[N,K](bf16)^T + bias ----------------
// EPI 0: QKV — Q/K cols -> outb (stride 1536), V cols -> outv transposed [b][h][d][s]
// EPI 1: gelu -> bf16 (stride N); EPI 2: outf += acc+bias (fp32 residual)
template<int EPI>
__global__ __launch_bounds__(256)
void gemm_kernel(const __hip_bfloat16* __restrict__ A,
                 const __hip_bfloat16* __restrict__ Bt,
                 const float* __restrict__ bias,
                 __hip_bfloat16* __restrict__ outb,
                 __hip_bfloat16* __restrict__ outv,
                 float* __restrict__ outf,
                 int M, int N, int K, int nTiles)
{
    __shared__ __hip_bfloat16 As[128*64];
    __shared__ __hip_bfloat16 Bs[128*64];

    const int tid  = threadIdx.x;
    const int lane = tid & 63;
    const int wid  = tid >> 6;

    const int nwg   = gridDim.x;
    const int chunk = nwg >> 3;
    const int bid   = blockIdx.x;
    const int swz   = (bid & 7) * chunk + (bid >> 3);
    const int m0 = (swz / nTiles) * 128;
    const int n0 = (swz % nTiles) * 128;

    const int srow = wid*32 + (lane >> 3);
    const int scol = ((lane & 7) ^ (srow & 7)) * 8;
    const __hip_bfloat16* aSrc = A  + (size_t)(m0 + srow) * K + scol;
    const __hip_bfloat16* bSrc = Bt + (size_t)(n0 + srow) * K + scol;
    char* aDst = (char*)As + wid*4096 + lane*16;
    char* bDst = (char*)Bs + wid*4096 + lane*16;

    f32x4 acc[4][4] = {};
    const int wm = wid >> 1, wn = wid & 1;
    const int cl = lane & 15, hi = lane >> 4;

    for (int kt = 0; kt < K; kt += 64) {
        __syncthreads();
#pragma unroll
        for (int i = 0; i < 4; ++i)
            gload16(aSrc + kt + (size_t)i*8*K, aDst + i*1024);
#pragma unroll
        for (int i = 0; i < 4; ++i)
            gload16(bSrc + kt + (size_t)i*8*K, bDst + i*1024);
        __syncthreads();

#pragma unroll
        for (int kk = 0; kk < 2; ++kk) {
            bf16x8 af[4], bfr[4];
#pragma unroll
            for (int m = 0; m < 4; ++m) {
                int row  = wm*64 + m*16 + cl;
                int slot = ((kk<<2) + hi) ^ (row & 7);
                af[m] = *(const bf16x8*)((const char*)As + row*128 + slot*16);
            }
#pragma unroll
            for (int n = 0; n < 4; ++n) {
                int row  = wn*64 + n*16 + cl;
                int slot = ((kk<<2) + hi) ^ (row & 7);
                bfr[n] = *(const bf16x8*)((const char*)Bs + row*128 + slot*16);
            }
#pragma unroll
            for (int m = 0; m < 4; ++m)
#pragma unroll
                for (int n = 0; n < 4; ++n)
                    acc[m][n] = __builtin_amdgcn_mfma_f32_16x16x32_bf16(af[m], bfr[n], acc[m][n], 0, 0, 0);
        }
    }

    const int rowBase = m0 + wm*64;
    const int colBase = n0 + wn*64;

    if constexpr (EPI == 0) {
        if (n0 < 1536) {   // Q/K region: store to qk buffer, stride 1536
#pragma unroll
            for (int n = 0; n < 4; ++n) {
                const int col = colBase + n*16 + cl;
                const float bv = bias[col];
#pragma unroll
                for (int m = 0; m < 4; ++m) {
#pragma unroll
                    for (int i = 0; i < 4; ++i) {
                        const int row = rowBase + m*16 + hi*4 + i;
                        outb[(size_t)row*1536 + col] = __float2bfloat16(acc[m][n][i] + bv);
                    }
                }
            }
        } else {           // V region: store transposed -> outv[(b*12+h)*64+d][s]
#pragma unroll
            for (int n = 0; n < 4; ++n) {
                const int col = colBase + n*16 + cl;
                const float bv = bias[col];
                const int hd = col - 1536;           // h*64 + d
                u16* vrow = (u16*)outv + (size_t)hd * 1024;
#pragma unroll
                for (int m = 0; m < 4; ++m) {
                    const int row0 = rowBase + m*16 + hi*4;
                    const int b = row0 >> 10, s0 = row0 & 1023;
                    ushort4 pk;
                    pk.x = f2bf_bits(acc[m][n][0] + bv);
                    pk.y = f2bf_bits(acc[m][n][1] + bv);
                    pk.z = f2bf_bits(acc[m][n][2] + bv);
                    pk.w = f2bf_bits(acc[m][n][3] + bv);
                    *(ushort4*)(vrow + (size_t)b*12*64*1024 + s0) = pk;
                }
            }
        }
    } else {
#pragma unroll
        for (int n = 0; n < 4; ++n) {
            const int col = colBase + n*16 + cl;
            const float bv = bias[col];
#pragma unroll
            for (int m = 0; m < 4; ++m) {
#pragma unroll
                for (int i = 0; i < 4; ++i) {
                    const int row = rowBase + m*16 + hi*4 + i;
                    float v = acc[m][n][i] + bv;
                    if constexpr (EPI == 1) {
                        float g = 0.5f * v * (1.0f + erff(v * 0.70710678118f));
                        outb[(size_t)row*N + col] = __float2bfloat16(g);
                    } else {
                        outf[(size_t)row*N + col] += v;
                    }
                }
            }
        }
    }
    (void)M;
}

// ---------------- flash attention, MFMA bf16, double-buffered staging ----------------
// Block = 4 waves, 64 q rows of one (b,h). 16 K/V tiles of 64.
// K from qk buffer [token][1536] (cols 768..1535); V^T from vt [(b*12+h)*64+d][1024].
__global__ __launch_bounds__(256)
void attn_kernel(const __hip_bfloat16* __restrict__ qkb, const __hip_bfloat16* __restrict__ vtb,
                 __hip_bfloat16* __restrict__ attno)
{
    __shared__ __align__(16) char Ks[2][8192];  // [t 64][d 64] bf16, slot^=(t&7)
    __shared__ __align__(16) char Vs[2][8192];  // [d 64][t 64] bf16, slot^=(d&7)
    __shared__ __align__(16) char Ps[8192];     // per-wave P: [q 16][t 64], slot^=(q&7)

    const u16* qk = (const u16*)qkb;
    const u16* vt = (const u16*)vtb;
    const int nwg = gridDim.x, bid = blockIdx.x, chunk = nwg >> 3;
    const int swz = (bid & 7) * chunk + (bid >> 3);
    const int bh = swz >> 4, qb = swz & 15;
    const int b = bh / H_, h = bh % H_;
    const int tid = threadIdx.x;
    const int lane = tid & 63, wid = tid >> 6;
    const int cl = lane & 15, hi = lane >> 4;
    const size_t browq = (size_t)(b*S_ + qb*64);

    // Q fragments: row = wid*16 + cl, k=d
    bf16x8 qf[2];
    {
        const u16* qp = qk + (browq + wid*16 + cl)*1536 + h*64;
        qf[0] = *(const bf16x8*)(qp + hi*8);
        qf[1] = *(const bf16x8*)(qp + 32 + hi*8);
    }

    // staging addresses (wave covers 16 rows: 2 gload rounds of 8)
    const int lrow = lane >> 3;                       // 0..7
    const int scol = ((lane & 7) ^ lrow) * 8;         // swizzled source col
    const u16* kbase = qk + ((size_t)b*S_ + wid*16 + lrow)*1536 + 768 + h*64 + scol;
    const u16* vbase = vt + (((size_t)(b*H_ + h))*64 + wid*16 + lrow)*1024 + scol;
    const int ldst = wid*2048 + lane*16;

    f32x4 acc_o[4] = {};
    float m_run = -1e30f;
    float l_part[4] = {0.f, 0.f, 0.f, 0.f};
    char* pbase = Ps + wid*2048;

    // prologue: stage tile 0 into buffer 0
    {
        gload16(kbase,                 Ks[0] + ldst);
        gload16(kbase + (size_t)8*1536, Ks[0] + ldst + 1024);
        gload16(vbase,                 Vs[0] + ldst);
        gload16(vbase + 8*1024,        Vs[0] + ldst + 1024);
    }

    for (int t = 0; t < 16; ++t) {
        __syncthreads();   // publishes tile t (compiler drains vmcnt before barrier)
        if (t < 15) {      // stage tile t+1 into other buffer while computing t
            const int nb = (t+1) & 1;
            const u16* kn = kbase + (size_t)(t+1)*64*1536;
            const u16* vn = vbase + (t+1)*64;
            gload16(kn,                  Ks[nb] + ldst);
            gload16(kn + (size_t)8*1536, Ks[nb] + ldst + 1024);
            gload16(vn,                  Vs[nb] + ldst);
            gload16(vn + 8*1024,         Vs[nb] + ldst + 1024);
        }
        const char* ks = Ks[t & 1];
        const char* vs = Vs[t & 1];

        // QK^T -> sc[n] (q=hi*4+i, t=n*16+cl)
        f32x4 sc[4] = {};
#pragma unroll
        for (int kk = 0; kk < 2; ++kk) {
            bf16x8 kf[4];
#pragma unroll
            for (int n = 0; n < 4; ++n) {
                const int row = n*16 + cl;
                kf[n] = *(const bf16x8*)(ks + row*128 + (((kk*4 + hi) ^ (cl & 7)) << 4));
            }
#pragma unroll
            for (int n = 0; n < 4; ++n)
                sc[n] = __builtin_amdgcn_mfma_f32_16x16x32_bf16(qf[kk], kf[n], sc[n], 0, 0, 0);
        }

#pragma unroll
        for (int n = 0; n < 4; ++n)
#pragma unroll
            for (int i = 0; i < 4; ++i)
                sc[n][i] *= 0.125f;

        // group max (shared across the 4 q-rows of this hi group) + defer-max
        float gmax = sc[0][0];
#pragma unroll
        for (int n = 0; n < 4; ++n)
#pragma unroll
            for (int i = 0; i < 4; ++i)
                gmax = fmaxf(gmax, sc[n][i]);
        gmax = fmaxf(gmax, __shfl_xor(gmax, 1));
        gmax = fmaxf(gmax, __shfl_xor(gmax, 2));
        gmax = fmaxf(gmax, __shfl_xor(gmax, 4));
        gmax = fmaxf(gmax, __shfl_xor(gmax, 8));
        if (gmax > m_run + 4.0f) {      // rescale only on significant growth
            const float corr = __expf(m_run - gmax);
            m_run = gmax;
#pragma unroll
            for (int i = 0; i < 4; ++i) l_part[i] *= corr;
#pragma unroll
            for (int nd = 0; nd < 4; ++nd)
#pragma unroll
                for (int i = 0; i < 4; ++i)
                    acc_o[nd][i] *= corr;
        }

        // P = exp(s - m), lane-partial row sums
#pragma unroll
        for (int n = 0; n < 4; ++n) {
#pragma unroll
            for (int i = 0; i < 4; ++i) {
                const float e = __expf(sc[n][i] - m_run);
                l_part[i] += e;
                const int q = hi*4 + i;
                const int slot = (n*2 + (cl >> 3)) ^ (q & 7);
                *(u16*)(pbase + q*128 + slot*16 + (cl & 7)*2) = f2bf_bits(e);
            }
        }

        // wave-local visibility of P writes
        asm volatile("s_waitcnt lgkmcnt(0)" ::: "memory");
        __builtin_amdgcn_sched_barrier(0);

        // PV: acc_o[nd] += P(frag A) * V^T(frag B)
#pragma unroll
        for (int kk = 0; kk < 2; ++kk) {
            const bf16x8 pf = *(const bf16x8*)(pbase + cl*128 + (((kk*4 + hi) ^ (cl & 7)) << 4));
            bf16x8 vf[4];
#pragma unroll
            for (int nd = 0; nd < 4; ++nd) {
                const int d = nd*16 + cl;
                vf[nd] = *(const bf16x8*)(vs + d*128 + (((kk*4 + hi) ^ (d & 7)) << 4));
            }
#pragma unroll
            for (int nd = 0; nd < 4; ++nd)
                acc_o[nd] = __builtin_amdgcn_mfma_f32_16x16x32_bf16(pf, vf[nd], acc_o[nd], 0, 0, 0);
        }
    }

    // epilogue: reduce l across the 16-lane row group, O /= l, store bf16
    u16* op = (u16*)attno;
#pragma unroll
    for (int i = 0; i < 4; ++i) {
        float l = l_part[i];
        l += __shfl_xor(l, 1);
        l += __shfl_xor(l, 2);
        l += __shfl_xor(l, 4);
        l += __shfl_xor(l, 8);
        const float inv = 1.f / l;
        const size_t row = browq + wid*16 + hi*4 + i;
#pragma unroll
        for (int nd = 0; nd < 4; ++nd)
            op[row*768 + h*64 + nd*16 + cl] = f2bf_bits(acc_o[nd][i] * inv);
    }
}

// ---------------- classifier ----------------
__global__ __launch_bounds__(256)
void cls_kernel(const float* __restrict__ x, const float* __restrict__ Wc,
                const float* __restrict__ bc, float* __restrict__ out)
{
    const int b = blockIdx.x;
    const float* xr = x + (size_t)b * S_ * D_;
    float a0 = 0.f, a1 = 0.f;
    for (int d = threadIdx.x; d < 768; d += 256) {
        float xv = xr[d];
        a0 += xv * Wc[d*2+0];
        a1 += xv * Wc[d*2+1];
    }
#pragma unroll
    for (int off = 32; off > 0; off >>= 1) { a0 += __shfl_xor(a0, off); a1 += __shfl_xor(a1, off); }
    __shared__ float r0[4], r1[4];
    const int w = threadIdx.x >> 6;
    if ((threadIdx.x & 63) == 0) { r0[w] = a0; r1[w] = a1; }
    __syncthreads();
    if (threadIdx.x == 0) {
        out[b*2+0] = r0[0]+r0[1]+r0[2]+r0[3] + bc[0];
        out[b*2+1] = r1[0]+r1[1]+r1[2]+r1[3] + bc[1];
    }
}

// ---------------- launch ----------------
extern "C" void kernel_launch(void* const* d_in, const int* in_sizes, int n_in,
                              void* d_out, int out_size, void* d_ws, size_t ws_size,
                              hipStream_t stream)
{
    const int*   tokens  = (const int*)  d_in[0];
    const float* tok_emb = (const float*)d_in[1];
    const float* pos_emb = (const float*)d_in[2];
    const float* e_s     = (const float*)d_in[3];
    const float* e_b     = (const float*)d_in[4];
    const float* Wq      = (const float*)d_in[5];
    const float* bq      = (const float*)d_in[6];
    const float* Wk      = (const float*)d_in[7];
    const float* bk      = (const float*)d_in[8];
    const float* Wv      = (const float*)d_in[9];
    const float* bv      = (const float*)d_in[10];
    const float* Wo      = (const float*)d_in[11];
    const float* bo      = (const float*)d_in[12];
    const float* l1s     = (const float*)d_in[13];
    const float* l1b     = (const float*)d_in[14];
    const float* l2s     = (const float*)d_in[15];
    const float* l2b     = (const float*)d_in[16];
    const float* W1      = (const float*)d_in[17];
    const float* b1      = (const float*)d_in[18];
    const float* W2      = (const float*)d_in[19];
    const float* b2      = (const float*)d_in[20];
    const float* Wc      = (const float*)d_in[21];
    const float* bc      = (const float*)d_in[22];
    (void)in_sizes; (void)n_in; (void)out_size;

    if (ws_size < 102346752) return;   // need ~102.4 MB

    char* ws = (char*)d_ws;
    __hip_bfloat16* wbuf = (__hip_bfloat16*)(ws + 0);          // 14,155,776 B
    float*          bqkv = (float*)(ws + 14155776);            //    110,592 B
    float*          x    = (float*)(ws + 14266368);            // 25,165,824 B
    __hip_bfloat16* xn   = (__hip_bfloat16*)(ws + 39432192);   // 12,582,912 B
    __hip_bfloat16* qk   = (__hip_bfloat16*)(ws + 52015104);   // 25,165,824 B [8192][1536]
    __hip_bfloat16* vT   = (__hip_bfloat16*)(ws + 77180928);   // 12,582,912 B [b*12+h][64][1024]
    __hip_bfloat16* att  = (__hip_bfloat16*)(ws + 89763840);   // 12,582,912 B (end 102,346,752)
    __hip_bfloat16* hbuf = qk;                                 // aliases qk+vT+att (50,331,648 B)

    __hip_bfloat16* wqkv_t = wbuf;
    __hip_bfloat16* wo_t   = wbuf + 1769472;
    __hip_bfloat16* w1_t   = wbuf + 2359296;
    __hip_bfloat16* w2_t   = wbuf + 4718592;

    prep_bqkv_kernel<<<108, 256, 0, stream>>>(bq, bk, bv, bqkv);
    embed_ln_kernel<<<2048, 256, 0, stream>>>(tokens, tok_emb, pos_emb, e_s, e_b, x);

    for (int l = 0; l < L_; ++l) {
        prep_layer_kernel<<<1728, 256, 0, stream>>>(Wq, Wk, Wv, Wo, W1, W2, l, wbuf);
        ln_kernel<<<2048, 256, 0, stream>>>(x, l1s + l*768, l1b + l*768, xn);
        gemm_kernel<0><<<1152, 256, 0, stream>>>(xn, wqkv_t, bqkv + l*2304, qk, vT, nullptr, NTOK, 2304, 768, 18);
        attn_kernel<<<1536, 256, 0, stream>>>(qk, vT, att);
        gemm_kernel<2><<<384, 256, 0, stream>>>(att, wo_t, bo + l*768, nullptr, nullptr, x, NTOK, 768, 768, 6);
        ln_kernel<<<2048, 256, 0, stream>>>(x, l2s + l*768, l2b + l*768, xn);
        gemm_kernel<1><<<1536, 256, 0, stream>>>(xn, w1_t, b1 + l*3072, hbuf, nullptr, nullptr, NTOK, 3072, 768, 24);
        gemm_kernel<2><<<384, 256, 0, stream>>>(hbuf, w2_t, b2 + l*768, nullptr, nullptr, x, NTOK, 768, 3072, 6);
    }
    cls_kernel<<<8, 256, 0, stream>>>(x, Wc, bc, (float*)d_out);
}

// Round 4
// 3362.709 us; speedup vs baseline: 2.9450x; 1.0700x over previous
//
#include <hip/hip_runtime.h>
#include <hip/hip_bf16.h>
#include <math.h>

// ---------------- constants ----------------
#define B_   8
#define S_   1024
#define D_   768
#define H_   12
#define HD_  64
#define L_   12
#define F_   3072
#define NTOK 8192   // B_*S_

typedef __bf16 bf16x8 __attribute__((ext_vector_type(8)));
typedef float  f32x4  __attribute__((ext_vector_type(4)));
typedef unsigned short u16;

static __device__ __forceinline__ unsigned short f2bf_bits(float f) {
    __hip_bfloat16 h = __float2bfloat16(f);
    return __builtin_bit_cast(unsigned short, h);
}
static __device__ __forceinline__ float bf2f(unsigned short u) {
    unsigned int t = ((unsigned int)u) << 16;
    return __builtin_bit_cast(float, t);
}
static __device__ __forceinline__ void gload16(const void* g, void* l) {
    __builtin_amdgcn_global_load_lds(
        (__attribute__((address_space(1))) void*)g,
        (__attribute__((address_space(3))) void*)l, 16, 0, 0);
}

// ---------------- weight prep: fp32 [R][C] -> bf16 transposed [C][R] ----------------
__global__ __launch_bounds__(256)
void prep_layer_kernel(const float* __restrict__ Wq, const float* __restrict__ Wk,
                       const float* __restrict__ Wv, const float* __restrict__ Wo,
                       const float* __restrict__ W1, const float* __restrict__ W2,
                       int l, __hip_bfloat16* __restrict__ wbuf)
{
    const int id = blockIdx.x;   // 0..1727
    const float* src; __hip_bfloat16* dst;
    int R, C, r0, c0;
    if (id < 432) {                       // q/k/v heads: src [768][64] per (which,h)
        int dtile = id % 12, t = id / 12; // t = which*12 + h
        int which = t / 12, h = t % 12;
        src = (which == 0 ? Wq : which == 1 ? Wk : Wv) + (size_t)(l*12 + h) * 768 * 64;
        dst = wbuf + (size_t)(which*768 + h*64) * 768;
        R = 768; C = 64; r0 = dtile * 64; c0 = 0;
    } else if (id < 576) {                // Wo: [768][768]
        int t = id - 432;
        src = Wo + (size_t)l * 768 * 768;
        dst = wbuf + 1769472;
        R = 768; C = 768; r0 = (t / 12) * 64; c0 = (t % 12) * 64;
    } else if (id < 1152) {               // W1: [768][3072]
        int t = id - 576;
        src = W1 + (size_t)l * 768 * 3072;
        dst = wbuf + 2359296;
        R = 768; C = 3072; r0 = (t % 12) * 64; c0 = (t / 12) * 64;
    } else {                              // W2: [3072][768]
        int t = id - 1152;
        src = W2 + (size_t)l * 3072 * 768;
        dst = wbuf + 4718592;
        R = 3072; C = 768; r0 = (t / 12) * 64; c0 = (t % 12) * 64;
    }
    __shared__ float tile[64][65];
    for (int i = threadIdx.x; i < 4096; i += 256) {
        int rr = i >> 6, cc = i & 63;
        tile[rr][cc] = src[(size_t)(r0 + rr) * C + (c0 + cc)];
    }
    __syncthreads();
    for (int i = threadIdx.x; i < 4096; i += 256) {
        int cc = i >> 6, rr = i & 63;
        dst[(size_t)(c0 + cc) * R + (r0 + rr)] = __float2bfloat16(tile[rr][cc]);
    }
}

__global__ __launch_bounds__(256)
void prep_bqkv_kernel(const float* __restrict__ bq, const float* __restrict__ bk,
                      const float* __restrict__ bv, float* __restrict__ bqkv)
{
    int i = blockIdx.x * 256 + threadIdx.x;   // < 12*2304
    int l = i / 2304, c = i % 2304;
    int which = c / 768, hk = c % 768;
    const float* src = which == 0 ? bq : which == 1 ? bk : bv;
    bqkv[i] = src[l*768 + hk];
}

// ---------------- embedding + LN -> x (fp32) ----------------
__global__ __launch_bounds__(256)
void embed_ln_kernel(const int* __restrict__ tokens, const float* __restrict__ tok_emb,
                     const float* __restrict__ pos_emb, const float* __restrict__ gam,
                     const float* __restrict__ bet, float* __restrict__ x)
{
    const int row  = blockIdx.x*4 + (threadIdx.x >> 6);
    const int lane = threadIdx.x & 63;
    const int s    = row & (S_-1);
    const int tok  = tokens[row];
    const float* te = tok_emb + (size_t)tok * D_;
    const float* pe = pos_emb + (size_t)s   * D_;
    float v[12]; float s1 = 0.f, s2 = 0.f;
#pragma unroll
    for (int c = 0; c < 3; ++c) {
        const int base = c*256 + lane*4;
        float4 a = *(const float4*)(te + base);
        float4 p = *(const float4*)(pe + base);
        float t0 = a.x+p.x, t1 = a.y+p.y, t2 = a.z+p.z, t3 = a.w+p.w;
        v[c*4+0]=t0; v[c*4+1]=t1; v[c*4+2]=t2; v[c*4+3]=t3;
        s1 += t0+t1+t2+t3;
        s2 += t0*t0 + t1*t1 + t2*t2 + t3*t3;
    }
#pragma unroll
    for (int off = 32; off > 0; off >>= 1) { s1 += __shfl_xor(s1, off); s2 += __shfl_xor(s2, off); }
    const float mean = s1 * (1.f/768.f);
    const float rstd = rsqrtf(s2*(1.f/768.f) - mean*mean + 1e-5f);
    float* xr = x + (size_t)row * D_;
#pragma unroll
    for (int c = 0; c < 3; ++c) {
        const int base = c*256 + lane*4;
        float4 g = *(const float4*)(gam + base);
        float4 bb = *(const float4*)(bet + base);
        float4 o;
        o.x = (v[c*4+0]-mean)*rstd*g.x + bb.x;
        o.y = (v[c*4+1]-mean)*rstd*g.y + bb.y;
        o.z = (v[c*4+2]-mean)*rstd*g.z + bb.z;
        o.w = (v[c*4+3]-mean)*rstd*g.w + bb.w;
        *(float4*)(xr + base) = o;
    }
}

// ---------------- LN: x (fp32) -> xn (bf16) ----------------
__global__ __launch_bounds__(256)
void ln_kernel(const float* __restrict__ xin, const float* __restrict__ gam,
               const float* __restrict__ bet, __hip_bfloat16* __restrict__ out)
{
    const int row  = blockIdx.x*4 + (threadIdx.x >> 6);
    const int lane = threadIdx.x & 63;
    const float* xr = xin + (size_t)row * D_;
    float v[12]; float s1 = 0.f, s2 = 0.f;
#pragma unroll
    for (int c = 0; c < 3; ++c) {
        float4 t = *(const float4*)(xr + c*256 + lane*4);
        v[c*4+0]=t.x; v[c*4+1]=t.y; v[c*4+2]=t.z; v[c*4+3]=t.w;
        s1 += t.x+t.y+t.z+t.w;
        s2 += t.x*t.x + t.y*t.y + t.z*t.z + t.w*t.w;
    }
#pragma unroll
    for (int off = 32; off > 0; off >>= 1) { s1 += __shfl_xor(s1, off); s2 += __shfl_xor(s2, off); }
    const float mean = s1 * (1.f/768.f);
    const float rstd = rsqrtf(s2*(1.f/768.f) - mean*mean + 1e-5f);
    unsigned short* op = (unsigned short*)out + (size_t)row * D_;
#pragma unroll
    for (int c = 0; c < 3; ++c) {
        const int base = c*256 + lane*4;
        float4 g = *(const float4*)(gam + base);
        float4 bb = *(const float4*)(bet + base);
        ushort4 pk;
        pk.x = f2bf_bits((v[c*4+0]-mean)*rstd*g.x + bb.x);
        pk.y = f2bf_bits((v[c*4+1]-mean)*rstd*g.y + bb.y);
        pk.z = f2bf_bits((v[c*4+2]-mean)*rstd*g.z + bb.z);
        pk.w = f2bf_bits((v[c*4+3]-mean)*rstd*g.w + bb.w);
        *(ushort4*)(op + base) = pk;
    }
}

// ---------------- GEMM 128x128: C = A * Bt^T + bias ----------------
// EPI 0: QKV — Q/K cols -> outb (stride 1536), V cols -> outv plain [8192][768]
// EPI 1: gelu(tanh form) -> bf16 (stride N)
template<int EPI>
__global__ __launch_bounds__(256)
void gemm_kernel(const __hip_bfloat16* __restrict__ A,
                 const __hip_bfloat16* __restrict__ Bt,
                 const float* __restrict__ bias,
                 __hip_bfloat16* __restrict__ outb,
                 __hip_bfloat16* __restrict__ outv,
                 int N, int K, int nTiles)
{
    __shared__ __hip_bfloat16 As[128*64];
    __shared__ __hip_bfloat16 Bs[128*64];

    const int tid  = threadIdx.x;
    const int lane = tid & 63;
    const int wid  = tid >> 6;

    const int nwg   = gridDim.x;
    const int chunk = nwg >> 3;
    const int bid   = blockIdx.x;
    const int swz   = (bid & 7) * chunk + (bid >> 3);
    const int m0 = (swz / nTiles) * 128;
    const int n0 = (swz % nTiles) * 128;

    const int srow = wid*32 + (lane >> 3);
    const int scol = ((lane & 7) ^ (srow & 7)) * 8;
    const __hip_bfloat16* aSrc = A  + (size_t)(m0 + srow) * K + scol;
    const __hip_bfloat16* bSrc = Bt + (size_t)(n0 + srow) * K + scol;
    char* aDst = (char*)As + wid*4096 + lane*16;
    char* bDst = (char*)Bs + wid*4096 + lane*16;

    f32x4 acc[4][4] = {};
    const int wm = wid >> 1, wn = wid & 1;
    const int cl = lane & 15, hi = lane >> 4;

    for (int kt = 0; kt < K; kt += 64) {
        __syncthreads();
#pragma unroll
        for (int i = 0; i < 4; ++i)
            gload16(aSrc + kt + (size_t)i*8*K, aDst + i*1024);
#pragma unroll
        for (int i = 0; i < 4; ++i)
            gload16(bSrc + kt + (size_t)i*8*K, bDst + i*1024);
        __syncthreads();

#pragma unroll
        for (int kk = 0; kk < 2; ++kk) {
            bf16x8 af[4], bfr[4];
#pragma unroll
            for (int m = 0; m < 4; ++m) {
                int row  = wm*64 + m*16 + cl;
                int slot = ((kk<<2) + hi) ^ (row & 7);
                af[m] = *(const bf16x8*)((const char*)As + row*128 + slot*16);
            }
#pragma unroll
            for (int n = 0; n < 4; ++n) {
                int row  = wn*64 + n*16 + cl;
                int slot = ((kk<<2) + hi) ^ (row & 7);
                bfr[n] = *(const bf16x8*)((const char*)Bs + row*128 + slot*16);
            }
#pragma unroll
            for (int m = 0; m < 4; ++m)
#pragma unroll
                for (int n = 0; n < 4; ++n)
                    acc[m][n] = __builtin_amdgcn_mfma_f32_16x16x32_bf16(af[m], bfr[n], acc[m][n], 0, 0, 0);
        }
    }

    const int rowBase = m0 + wm*64;
    const int colBase = n0 + wn*64;

    if constexpr (EPI == 0) {
        if (n0 < 1536) {   // Q/K region: store to qk buffer, stride 1536
#pragma unroll
            for (int n = 0; n < 4; ++n) {
                const int col = colBase + n*16 + cl;
                const float bv = bias[col];
#pragma unroll
                for (int m = 0; m < 4; ++m) {
#pragma unroll
                    for (int i = 0; i < 4; ++i) {
                        const int row = rowBase + m*16 + hi*4 + i;
                        outb[(size_t)row*1536 + col] = __float2bfloat16(acc[m][n][i] + bv);
                    }
                }
            }
        } else {           // V region: plain store [8192][768]
#pragma unroll
            for (int n = 0; n < 4; ++n) {
                const int col = colBase + n*16 + cl;
                const float bv = bias[col];
                const int hd = col - 1536;
#pragma unroll
                for (int m = 0; m < 4; ++m) {
#pragma unroll
                    for (int i = 0; i < 4; ++i) {
                        const int row = rowBase + m*16 + hi*4 + i;
                        outv[(size_t)row*768 + hd] = __float2bfloat16(acc[m][n][i] + bv);
                    }
                }
            }
        }
    } else {               // gelu (tanh form) -> bf16
#pragma unroll
        for (int n = 0; n < 4; ++n) {
            const int col = colBase + n*16 + cl;
            const float bv = bias[col];
#pragma unroll
            for (int m = 0; m < 4; ++m) {
#pragma unroll
                for (int i = 0; i < 4; ++i) {
                    const int row = rowBase + m*16 + hi*4 + i;
                    const float v = acc[m][n][i] + bv;
                    const float y = 0.7978845608f * (v + 0.044715f*v*v*v);
                    const float e = __expf(-2.0f * fabsf(y));
                    const float th = (1.0f - e) / (1.0f + e);
                    const float g = 0.5f * v * (1.0f + copysignf(th, y));
                    outb[(size_t)row*N + col] = __float2bfloat16(g);
                }
            }
        }
    }
}

// ---------------- GEMM 64x128, 4 waves (wave-tile 32x64): outf += A*Bt^T + bias ---------
// For small-N GEMMs (Wo, FFN2): 2x the grid of the 128x128 variant.
__global__ __launch_bounds__(256)
void gemm64_res_kernel(const __hip_bfloat16* __restrict__ A,
                       const __hip_bfloat16* __restrict__ Bt,
                       const float* __restrict__ bias,
                       float* __restrict__ outf,
                       int N, int K, int nTiles)
{
    __shared__ __hip_bfloat16 As[64*64];
    __shared__ __hip_bfloat16 Bs[128*64];

    const int tid  = threadIdx.x;
    const int lane = tid & 63;
    const int wid  = tid >> 6;

    const int nwg   = gridDim.x;
    const int chunk = nwg >> 3;
    const int bid   = blockIdx.x;
    const int swz   = (bid & 7) * chunk + (bid >> 3);
    const int m0 = (swz / nTiles) * 64;
    const int n0 = (swz % nTiles) * 128;

    const int lrow = lane >> 3;
    const int scol = ((lane & 7) ^ lrow) * 8;
    const __hip_bfloat16* aSrc = A  + (size_t)(m0 + wid*16 + lrow) * K + scol;
    const __hip_bfloat16* bSrc = Bt + (size_t)(n0 + wid*32 + lrow) * K + scol;
    char* aDst = (char*)As + wid*2048 + lane*16;
    char* bDst = (char*)Bs + wid*4096 + lane*16;

    f32x4 acc[2][4] = {};
    const int wm = wid >> 1, wn = wid & 1;
    const int cl = lane & 15, hi = lane >> 4;

    for (int kt = 0; kt < K; kt += 64) {
        __syncthreads();
#pragma unroll
        for (int i = 0; i < 2; ++i)
            gload16(aSrc + kt + (size_t)i*8*K, aDst + i*1024);
#pragma unroll
        for (int i = 0; i < 4; ++i)
            gload16(bSrc + kt + (size_t)i*8*K, bDst + i*1024);
        __syncthreads();

#pragma unroll
        for (int kk = 0; kk < 2; ++kk) {
            bf16x8 af[2], bfr[4];
#pragma unroll
            for (int m = 0; m < 2; ++m) {
                int row  = wm*32 + m*16 + cl;
                int slot = ((kk<<2) + hi) ^ (row & 7);
                af[m] = *(const bf16x8*)((const char*)As + row*128 + slot*16);
            }
#pragma unroll
            for (int n = 0; n < 4; ++n) {
                int row  = wn*64 + n*16 + cl;
                int slot = ((kk<<2) + hi) ^ (row & 7);
                bfr[n] = *(const bf16x8*)((const char*)Bs + row*128 + slot*16);
            }
#pragma unroll
            for (int m = 0; m < 2; ++m)
#pragma unroll
                for (int n = 0; n < 4; ++n)
                    acc[m][n] = __builtin_amdgcn_mfma_f32_16x16x32_bf16(af[m], bfr[n], acc[m][n], 0, 0, 0);
        }
    }

    const int rowBase = m0 + wm*32;
    const int colBase = n0 + wn*64;
#pragma unroll
    for (int n = 0; n < 4; ++n) {
        const int col = colBase + n*16 + cl;
        const float bv = bias[col];
#pragma unroll
        for (int m = 0; m < 2; ++m) {
#pragma unroll
            for (int i = 0; i < 4; ++i) {
                const int row = rowBase + m*16 + hi*4 + i;
                outf[(size_t)row*N + col] += acc[m][n][i] + bv;
            }
        }
    }
}

// ---------------- V transpose: vplain [8192][768] -> vT [(b*768+hd)][1024] ----------------
__global__ __launch_bounds__(256)
void vtrans_kernel(const __hip_bfloat16* __restrict__ vp, __hip_bfloat16* __restrict__ vT)
{
    __shared__ u16 tile[64][65];
    const int id = blockIdx.x;              // 8 * 12 * 16 = 1536
    const int b = id / 192, r = id % 192;
    const int hdt = r / 16, st = r % 16;
    const u16* src = (const u16*)vp + ((size_t)(b*1024 + st*64))*768 + hdt*64;
    u16* dst = (u16*)vT + ((size_t)(b*768 + hdt*64))*1024 + st*64;
    for (int i = threadIdx.x; i < 4096; i += 256) {
        int rr = i >> 6, cc = i & 63;
        tile[rr][cc] = src[(size_t)rr*768 + cc];
    }
    __syncthreads();
    for (int i = threadIdx.x; i < 4096; i += 256) {
        int cc = i >> 6, rr = i & 63;
        dst[(size_t)cc*1024 + rr] = tile[rr][cc];
    }
}

// ---------------- flash attention, MFMA bf16, double-buffered staging ----------------
__global__ __launch_bounds__(256)
void attn_kernel(const __hip_bfloat16* __restrict__ qkb, const __hip_bfloat16* __restrict__ vtb,
                 __hip_bfloat16* __restrict__ attno)
{
    __shared__ __align__(16) char Ks[2][8192];  // [t 64][d 64] bf16, slot^=(t&7)
    __shared__ __align__(16) char Vs[2][8192];  // [d 64][t 64] bf16, slot^=(d&7)
    __shared__ __align__(16) char Ps[8192];     // per-wave P: [q 16][t 64], slot^=(q&7)

    const u16* qk = (const u16*)qkb;
    const u16* vt = (const u16*)vtb;
    const int nwg = gridDim.x, bid = blockIdx.x, chunk = nwg >> 3;
    const int swz = (bid & 7) * chunk + (bid >> 3);
    const int bh = swz >> 4, qb = swz & 15;
    const int b = bh / H_, h = bh % H_;
    const int tid = threadIdx.x;
    const int lane = tid & 63, wid = tid >> 6;
    const int cl = lane & 15, hi = lane >> 4;
    const size_t browq = (size_t)(b*S_ + qb*64);

    bf16x8 qf[2];
    {
        const u16* qp = qk + (browq + wid*16 + cl)*1536 + h*64;
        qf[0] = *(const bf16x8*)(qp + hi*8);
        qf[1] = *(const bf16x8*)(qp + 32 + hi*8);
    }

    const int lrow = lane >> 3;
    const int scol = ((lane & 7) ^ lrow) * 8;
    const u16* kbase = qk + ((size_t)b*S_ + wid*16 + lrow)*1536 + 768 + h*64 + scol;
    const u16* vbase = vt + (((size_t)(b*H_ + h))*64 + wid*16 + lrow)*1024 + scol;
    const int ldst = wid*2048 + lane*16;

    f32x4 acc_o[4] = {};
    float m_run = -1e30f;
    float l_part[4] = {0.f, 0.f, 0.f, 0.f};
    char* pbase = Ps + wid*2048;

    {
        gload16(kbase,                  Ks[0] + ldst);
        gload16(kbase + (size_t)8*1536, Ks[0] + ldst + 1024);
        gload16(vbase,                  Vs[0] + ldst);
        gload16(vbase + 8*1024,         Vs[0] + ldst + 1024);
    }

    for (int t = 0; t < 16; ++t) {
        __syncthreads();
        if (t < 15) {
            const int nb = (t+1) & 1;
            const u16* kn = kbase + (size_t)(t+1)*64*1536;
            const u16* vn = vbase + (t+1)*64;
            gload16(kn,                  Ks[nb] + ldst);
            gload16(kn + (size_t)8*1536, Ks[nb] + ldst + 1024);
            gload16(vn,                  Vs[nb] + ldst);
            gload16(vn + 8*1024,         Vs[nb] + ldst + 1024);
        }
        const char* ks = Ks[t & 1];
        const char* vs = Vs[t & 1];

        f32x4 sc[4] = {};
#pragma unroll
        for (int kk = 0; kk < 2; ++kk) {
            bf16x8 kf[4];
#pragma unroll
            for (int n = 0; n < 4; ++n) {
                const int row = n*16 + cl;
                kf[n] = *(const bf16x8*)(ks + row*128 + (((kk*4 + hi) ^ (cl & 7)) << 4));
            }
#pragma unroll
            for (int n = 0; n < 4; ++n)
                sc[n] = __builtin_amdgcn_mfma_f32_16x16x32_bf16(qf[kk], kf[n], sc[n], 0, 0, 0);
        }

#pragma unroll
        for (int n = 0; n < 4; ++n)
#pragma unroll
            for (int i = 0; i < 4; ++i)
                sc[n][i] *= 0.125f;

        float gmax = sc[0][0];
#pragma unroll
        for (int n = 0; n < 4; ++n)
#pragma unroll
            for (int i = 0; i < 4; ++i)
                gmax = fmaxf(gmax, sc[n][i]);
        gmax = fmaxf(gmax, __shfl_xor(gmax, 1));
        gmax = fmaxf(gmax, __shfl_xor(gmax, 2));
        gmax = fmaxf(gmax, __shfl_xor(gmax, 4));
        gmax = fmaxf(gmax, __shfl_xor(gmax, 8));
        if (gmax > m_run + 4.0f) {
            const float corr = __expf(m_run - gmax);
            m_run = gmax;
#pragma unroll
            for (int i = 0; i < 4; ++i) l_part[i] *= corr;
#pragma unroll
            for (int nd = 0; nd < 4; ++nd)
#pragma unroll
                for (int i = 0; i < 4; ++i)
                    acc_o[nd][i] *= corr;
        }

#pragma unroll
        for (int n = 0; n < 4; ++n) {
#pragma unroll
            for (int i = 0; i < 4; ++i) {
                const float e = __expf(sc[n][i] - m_run);
                l_part[i] += e;
                const int q = hi*4 + i;
                const int slot = (n*2 + (cl >> 3)) ^ (q & 7);
                *(u16*)(pbase + q*128 + slot*16 + (cl & 7)*2) = f2bf_bits(e);
            }
        }

        asm volatile("s_waitcnt lgkmcnt(0)" ::: "memory");
        __builtin_amdgcn_sched_barrier(0);

#pragma unroll
        for (int kk = 0; kk < 2; ++kk) {
            const bf16x8 pf = *(const bf16x8*)(pbase + cl*128 + (((kk*4 + hi) ^ (cl & 7)) << 4));
            bf16x8 vf[4];
#pragma unroll
            for (int nd = 0; nd < 4; ++nd) {
                const int d = nd*16 + cl;
                vf[nd] = *(const bf16x8*)(vs + d*128 + (((kk*4 + hi) ^ (d & 7)) << 4));
            }
#pragma unroll
            for (int nd = 0; nd < 4; ++nd)
                acc_o[nd] = __builtin_amdgcn_mfma_f32_16x16x32_bf16(pf, vf[nd], acc_o[nd], 0, 0, 0);
        }
    }

    u16* op = (u16*)attno;
#pragma unroll
    for (int i = 0; i < 4; ++i) {
        float l = l_part[i];
        l += __shfl_xor(l, 1);
        l += __shfl_xor(l, 2);
        l += __shfl_xor(l, 4);
        l += __shfl_xor(l, 8);
        const float inv = 1.f / l;
        const size_t row = browq + wid*16 + hi*4 + i;
#pragma unroll
        for (int nd = 0; nd < 4; ++nd)
            op[row*768 + h*64 + nd*16 + cl] = f2bf_bits(acc_o[nd][i] * inv);
    }
}

// ---------------- classifier ----------------
__global__ __launch_bounds__(256)
void cls_kernel(const float* __restrict__ x, const float* __restrict__ Wc,
                const float* __restrict__ bc, float* __restrict__ out)
{
    const int b = blockIdx.x;
    const float* xr = x + (size_t)b * S_ * D_;
    float a0 = 0.f, a1 = 0.f;
    for (int d = threadIdx.x; d < 768; d += 256) {
        float xv = xr[d];
        a0 += xv * Wc[d*2+0];
        a1 += xv * Wc[d*2+1];
    }
#pragma unroll
    for (int off = 32; off > 0; off >>= 1) { a0 += __shfl_xor(a0, off); a1 += __shfl_xor(a1, off); }
    __shared__ float r0[4], r1[4];
    const int w = threadIdx.x >> 6;
    if ((threadIdx.x & 63) == 0) { r0[w] = a0; r1[w] = a1; }
    __syncthreads();
    if (threadIdx.x == 0) {
        out[b*2+0] = r0[0]+r0[1]+r0[2]+r0[3] + bc[0];
        out[b*2+1] = r1[0]+r1[1]+r1[2]+r1[3] + bc[1];
    }
}

// ---------------- launch ----------------
extern "C" void kernel_launch(void* const* d_in, const int* in_sizes, int n_in,
                              void* d_out, int out_size, void* d_ws, size_t ws_size,
                              hipStream_t stream)
{
    const int*   tokens  = (const int*)  d_in[0];
    const float* tok_emb = (const float*)d_in[1];
    const float* pos_emb = (const float*)d_in[2];
    const float* e_s     = (const float*)d_in[3];
    const float* e_b     = (const float*)d_in[4];
    const float* Wq      = (const float*)d_in[5];
    const float* bq      = (const float*)d_in[6];
    const float* Wk      = (const float*)d_in[7];
    const float* bk      = (const float*)d_in[8];
    const float* Wv      = (const float*)d_in[9];
    const float* bv      = (const float*)d_in[10];
    const float* Wo      = (const float*)d_in[11];
    const float* bo      = (const float*)d_in[12];
    const float* l1s     = (const float*)d_in[13];
    const float* l1b     = (const float*)d_in[14];
    const float* l2s     = (const float*)d_in[15];
    const float* l2b     = (const float*)d_in[16];
    const float* W1      = (const float*)d_in[17];
    const float* b1      = (const float*)d_in[18];
    const float* W2      = (const float*)d_in[19];
    const float* b2      = (const float*)d_in[20];
    const float* Wc      = (const float*)d_in[21];
    const float* bc      = (const float*)d_in[22];
    (void)in_sizes; (void)n_in; (void)out_size;

    if (ws_size < 102346752) return;   // need ~102.4 MB

    char* ws = (char*)d_ws;
    __hip_bfloat16* wbuf = (__hip_bfloat16*)(ws + 0);          // 14,155,776 B
    float*          bqkv = (float*)(ws + 14155776);            //    110,592 B
    float*          x    = (float*)(ws + 14266368);            // 25,165,824 B
    __hip_bfloat16* xn   = (__hip_bfloat16*)(ws + 39432192);   // 12,582,912 B
    __hip_bfloat16* qk   = (__hip_bfloat16*)(ws + 52015104);   // 25,165,824 B [8192][1536]
    __hip_bfloat16* vT   = (__hip_bfloat16*)(ws + 77180928);   // 12,582,912 B [b*768+hd][1024]
    __hip_bfloat16* att  = (__hip_bfloat16*)(ws + 89763840);   // 12,582,912 B (end 102,346,752)
    __hip_bfloat16* vpl  = att;                                // V plain [8192][768] (dead before attn writes)
    __hip_bfloat16* hbuf = qk;                                 // aliases qk+vT+att (50,331,648 B)

    __hip_bfloat16* wqkv_t = wbuf;
    __hip_bfloat16* wo_t   = wbuf + 1769472;
    __hip_bfloat16* w1_t   = wbuf + 2359296;
    __hip_bfloat16* w2_t   = wbuf + 4718592;

    prep_bqkv_kernel<<<108, 256, 0, stream>>>(bq, bk, bv, bqkv);
    embed_ln_kernel<<<2048, 256, 0, stream>>>(tokens, tok_emb, pos_emb, e_s, e_b, x);

    for (int l = 0; l < L_; ++l) {
        prep_layer_kernel<<<1728, 256, 0, stream>>>(Wq, Wk, Wv, Wo, W1, W2, l, wbuf);
        ln_kernel<<<2048, 256, 0, stream>>>(x, l1s + l*768, l1b + l*768, xn);
        gemm_kernel<0><<<1152, 256, 0, stream>>>(xn, wqkv_t, bqkv + l*2304, qk, vpl, 2304, 768, 18);
        vtrans_kernel<<<1536, 256, 0, stream>>>(vpl, vT);
        attn_kernel<<<1536, 256, 0, stream>>>(qk, vT, att);
        gemm64_res_kernel<<<768, 256, 0, stream>>>(att, wo_t, bo + l*768, x, 768, 768, 6);
        ln_kernel<<<2048, 256, 0, stream>>>(x, l2s + l*768, l2b + l*768, xn);
        gemm_kernel<1><<<1536, 256, 0, stream>>>(xn, w1_t, b1 + l*3072, hbuf, nullptr, 3072, 768, 24);
        gemm64_res_kernel<<<768, 256, 0, stream>>>(hbuf, w2_t, b2 + l*768, x, 768, 3072, 6);
    }
    cls_kernel<<<8, 256, 0, stream>>>(x, Wc, bc, (float*)d_out);
}

// Round 5
// 3241.320 us; speedup vs baseline: 3.0553x; 1.0375x over previous
//
#include <hip/hip_runtime.h>
#include <hip/hip_bf16.h>
#include <math.h>

// ---------------- constants ----------------
#define B_   8
#define S_   1024
#define D_   768
#define H_   12
#define HD_  64
#define L_   12
#define F_   3072
#define NTOK 8192   // B_*S_

typedef __bf16 bf16x8 __attribute__((ext_vector_type(8)));
typedef float  f32x4  __attribute__((ext_vector_type(4)));
typedef unsigned short u16;

static __device__ __forceinline__ unsigned short f2bf_bits(float f) {
    __hip_bfloat16 h = __float2bfloat16(f);
    return __builtin_bit_cast(unsigned short, h);
}
static __device__ __forceinline__ float bf2f(unsigned short u) {
    unsigned int t = ((unsigned int)u) << 16;
    return __builtin_bit_cast(float, t);
}
static __device__ __forceinline__ void gload16(const void* g, void* l) {
    __builtin_amdgcn_global_load_lds(
        (__attribute__((address_space(1))) void*)g,
        (__attribute__((address_space(3))) void*)l, 16, 0, 0);
}

// ---------------- weight prep: fp32 [R][C] -> bf16 transposed [C][R] ----------------
__global__ __launch_bounds__(256)
void prep_layer_kernel(const float* __restrict__ Wq, const float* __restrict__ Wk,
                       const float* __restrict__ Wv, const float* __restrict__ Wo,
                       const float* __restrict__ W1, const float* __restrict__ W2,
                       int l, __hip_bfloat16* __restrict__ wbuf)
{
    const int id = blockIdx.x;   // 0..1727
    const float* src; __hip_bfloat16* dst;
    int R, C, r0, c0;
    if (id < 432) {                       // q/k/v heads: src [768][64] per (which,h)
        int dtile = id % 12, t = id / 12; // t = which*12 + h
        int which = t / 12, h = t % 12;
        src = (which == 0 ? Wq : which == 1 ? Wk : Wv) + (size_t)(l*12 + h) * 768 * 64;
        dst = wbuf + (size_t)(which*768 + h*64) * 768;
        R = 768; C = 64; r0 = dtile * 64; c0 = 0;
    } else if (id < 576) {                // Wo: [768][768]
        int t = id - 432;
        src = Wo + (size_t)l * 768 * 768;
        dst = wbuf + 1769472;
        R = 768; C = 768; r0 = (t / 12) * 64; c0 = (t % 12) * 64;
    } else if (id < 1152) {               // W1: [768][3072]
        int t = id - 576;
        src = W1 + (size_t)l * 768 * 3072;
        dst = wbuf + 2359296;
        R = 768; C = 3072; r0 = (t % 12) * 64; c0 = (t / 12) * 64;
    } else {                              // W2: [3072][768]
        int t = id - 1152;
        src = W2 + (size_t)l * 3072 * 768;
        dst = wbuf + 4718592;
        R = 3072; C = 768; r0 = (t / 12) * 64; c0 = (t % 12) * 64;
    }
    __shared__ float tile[64][65];
    for (int i = threadIdx.x; i < 4096; i += 256) {
        int rr = i >> 6, cc = i & 63;
        tile[rr][cc] = src[(size_t)(r0 + rr) * C + (c0 + cc)];
    }
    __syncthreads();
    for (int i = threadIdx.x; i < 4096; i += 256) {
        int cc = i >> 6, rr = i & 63;
        dst[(size_t)(c0 + cc) * R + (r0 + rr)] = __float2bfloat16(tile[rr][cc]);
    }
}

__global__ __launch_bounds__(256)
void prep_bqkv_kernel(const float* __restrict__ bq, const float* __restrict__ bk,
                      const float* __restrict__ bv, float* __restrict__ bqkv)
{
    int i = blockIdx.x * 256 + threadIdx.x;   // < 12*2304
    int l = i / 2304, c = i % 2304;
    int which = c / 768, hk = c % 768;
    const float* src = which == 0 ? bq : which == 1 ? bk : bv;
    bqkv[i] = src[l*768 + hk];
}

// ---------------- embedding + LN -> x (fp32) ----------------
__global__ __launch_bounds__(256)
void embed_ln_kernel(const int* __restrict__ tokens, const float* __restrict__ tok_emb,
                     const float* __restrict__ pos_emb, const float* __restrict__ gam,
                     const float* __restrict__ bet, float* __restrict__ x)
{
    const int row  = blockIdx.x*4 + (threadIdx.x >> 6);
    const int lane = threadIdx.x & 63;
    const int s    = row & (S_-1);
    const int tok  = tokens[row];
    const float* te = tok_emb + (size_t)tok * D_;
    const float* pe = pos_emb + (size_t)s   * D_;
    float v[12]; float s1 = 0.f, s2 = 0.f;
#pragma unroll
    for (int c = 0; c < 3; ++c) {
        const int base = c*256 + lane*4;
        float4 a = *(const float4*)(te + base);
        float4 p = *(const float4*)(pe + base);
        float t0 = a.x+p.x, t1 = a.y+p.y, t2 = a.z+p.z, t3 = a.w+p.w;
        v[c*4+0]=t0; v[c*4+1]=t1; v[c*4+2]=t2; v[c*4+3]=t3;
        s1 += t0+t1+t2+t3;
        s2 += t0*t0 + t1*t1 + t2*t2 + t3*t3;
    }
#pragma unroll
    for (int off = 32; off > 0; off >>= 1) { s1 += __shfl_xor(s1, off); s2 += __shfl_xor(s2, off); }
    const float mean = s1 * (1.f/768.f);
    const float rstd = rsqrtf(s2*(1.f/768.f) - mean*mean + 1e-5f);
    float* xr = x + (size_t)row * D_;
#pragma unroll
    for (int c = 0; c < 3; ++c) {
        const int base = c*256 + lane*4;
        float4 g = *(const float4*)(gam + base);
        float4 bb = *(const float4*)(bet + base);
        float4 o;
        o.x = (v[c*4+0]-mean)*rstd*g.x + bb.x;
        o.y = (v[c*4+1]-mean)*rstd*g.y + bb.y;
        o.z = (v[c*4+2]-mean)*rstd*g.z + bb.z;
        o.w = (v[c*4+3]-mean)*rstd*g.w + bb.w;
        *(float4*)(xr + base) = o;
    }
}

// ---------------- LN: x (fp32) -> xn (bf16) ----------------
__global__ __launch_bounds__(256)
void ln_kernel(const float* __restrict__ xin, const float* __restrict__ gam,
               const float* __restrict__ bet, __hip_bfloat16* __restrict__ out)
{
    const int row  = blockIdx.x*4 + (threadIdx.x >> 6);
    const int lane = threadIdx.x & 63;
    const float* xr = xin + (size_t)row * D_;
    float v[12]; float s1 = 0.f, s2 = 0.f;
#pragma unroll
    for (int c = 0; c < 3; ++c) {
        float4 t = *(const float4*)(xr + c*256 + lane*4);
        v[c*4+0]=t.x; v[c*4+1]=t.y; v[c*4+2]=t.z; v[c*4+3]=t.w;
        s1 += t.x+t.y+t.z+t.w;
        s2 += t.x*t.x + t.y*t.y + t.z*t.z + t.w*t.w;
    }
#pragma unroll
    for (int off = 32; off > 0; off >>= 1) { s1 += __shfl_xor(s1, off); s2 += __shfl_xor(s2, off); }
    const float mean = s1 * (1.f/768.f);
    const float rstd = rsqrtf(s2*(1.f/768.f) - mean*mean + 1e-5f);
    unsigned short* op = (unsigned short*)out + (size_t)row * D_;
#pragma unroll
    for (int c = 0; c < 3; ++c) {
        const int base = c*256 + lane*4;
        float4 g = *(const float4*)(gam + base);
        float4 bb = *(const float4*)(bet + base);
        ushort4 pk;
        pk.x = f2bf_bits((v[c*4+0]-mean)*rstd*g.x + bb.x);
        pk.y = f2bf_bits((v[c*4+1]-mean)*rstd*g.y + bb.y);
        pk.z = f2bf_bits((v[c*4+2]-mean)*rstd*g.z + bb.z);
        pk.w = f2bf_bits((v[c*4+3]-mean)*rstd*g.w + bb.w);
        *(ushort4*)(op + base) = pk;
    }
}

// ---------------- GEMM 128x128: C = A * Bt^T + bias ----------------
// EPI 0: QKV — Q/K cols -> outb (stride 1536); V cols -> outv = V^T [(b*768+hd)][1024]
//        (V^T produced via in-LDS transpose of the 128x128 tile, coalesced stores)
// EPI 1: gelu(tanh form) -> bf16 (stride N)
template<int EPI>
__global__ __launch_bounds__(256)
void gemm_kernel(const __hip_bfloat16* __restrict__ A,
                 const __hip_bfloat16* __restrict__ Bt,
                 const float* __restrict__ bias,
                 __hip_bfloat16* __restrict__ outb,
                 __hip_bfloat16* __restrict__ outv,
                 int N, int K, int nTiles)
{
    __shared__ __align__(16) char smem[32768];
    __hip_bfloat16* As = (__hip_bfloat16*)smem;
    __hip_bfloat16* Bs = (__hip_bfloat16*)(smem + 16384);

    const int tid  = threadIdx.x;
    const int lane = tid & 63;
    const int wid  = tid >> 6;

    const int nwg   = gridDim.x;
    const int chunk = nwg >> 3;
    const int bid   = blockIdx.x;
    const int swz   = (bid & 7) * chunk + (bid >> 3);
    const int m0 = (swz / nTiles) * 128;
    const int n0 = (swz % nTiles) * 128;

    const int srow = wid*32 + (lane >> 3);
    const int scol = ((lane & 7) ^ (srow & 7)) * 8;
    const __hip_bfloat16* aSrc = A  + (size_t)(m0 + srow) * K + scol;
    const __hip_bfloat16* bSrc = Bt + (size_t)(n0 + srow) * K + scol;
    char* aDst = (char*)As + wid*4096 + lane*16;
    char* bDst = (char*)Bs + wid*4096 + lane*16;

    f32x4 acc[4][4] = {};
    const int wm = wid >> 1, wn = wid & 1;
    const int cl = lane & 15, hi = lane >> 4;

    for (int kt = 0; kt < K; kt += 64) {
        __syncthreads();
#pragma unroll
        for (int i = 0; i < 4; ++i)
            gload16(aSrc + kt + (size_t)i*8*K, aDst + i*1024);
#pragma unroll
        for (int i = 0; i < 4; ++i)
            gload16(bSrc + kt + (size_t)i*8*K, bDst + i*1024);
        __syncthreads();

#pragma unroll
        for (int kk = 0; kk < 2; ++kk) {
            bf16x8 af[4], bfr[4];
#pragma unroll
            for (int m = 0; m < 4; ++m) {
                int row  = wm*64 + m*16 + cl;
                int slot = ((kk<<2) + hi) ^ (row & 7);
                af[m] = *(const bf16x8*)((const char*)As + row*128 + slot*16);
            }
#pragma unroll
            for (int n = 0; n < 4; ++n) {
                int row  = wn*64 + n*16 + cl;
                int slot = ((kk<<2) + hi) ^ (row & 7);
                bfr[n] = *(const bf16x8*)((const char*)Bs + row*128 + slot*16);
            }
#pragma unroll
            for (int m = 0; m < 4; ++m)
#pragma unroll
                for (int n = 0; n < 4; ++n)
                    acc[m][n] = __builtin_amdgcn_mfma_f32_16x16x32_bf16(af[m], bfr[n], acc[m][n], 0, 0, 0);
        }
    }

    const int rowBase = m0 + wm*64;
    const int colBase = n0 + wn*64;

    if constexpr (EPI == 0) {
        if (n0 < 1536) {   // Q/K region: store to qk buffer, stride 1536
#pragma unroll
            for (int n = 0; n < 4; ++n) {
                const int col = colBase + n*16 + cl;
                const float bv = bias[col];
#pragma unroll
                for (int m = 0; m < 4; ++m) {
#pragma unroll
                    for (int i = 0; i < 4; ++i) {
                        const int row = rowBase + m*16 + hi*4 + i;
                        outb[(size_t)row*1536 + col] = __float2bfloat16(acc[m][n][i] + bv);
                    }
                }
            }
        } else {
            // V region: transpose 128x128 tile in LDS, store V^T coalesced.
            // T layout (bytes): hd*256 + ((s>>3)^(hd&15))*16 + (s&7)*2
            __syncthreads();   // staging LDS now dead; safe to reuse
#pragma unroll
            for (int n = 0; n < 4; ++n) {
                const int col = colBase + n*16 + cl;
                const float bv = bias[col];
                const int hdl = wn*64 + n*16 + cl;
#pragma unroll
                for (int m = 0; m < 4; ++m) {
                    const int sl = wm*64 + m*16 + hi*4;
                    ushort4 pk;
                    pk.x = f2bf_bits(acc[m][n][0] + bv);
                    pk.y = f2bf_bits(acc[m][n][1] + bv);
                    pk.z = f2bf_bits(acc[m][n][2] + bv);
                    pk.w = f2bf_bits(acc[m][n][3] + bv);
                    *(ushort4*)(smem + hdl*256 + ((((sl >> 3) ^ (hdl & 15))) << 4) + (sl & 7)*2) = pk;
                }
            }
            __syncthreads();
            const int hdl2 = tid >> 1;            // 0..127
            const int sh   = (tid & 1) * 64;      // 0 or 64
            const int hdg  = (n0 - 1536) + hdl2;  // h*64+d
            const int bb   = m0 >> 10;
            u16* dst = (u16*)outv + ((size_t)(bb*768) + hdg)*1024 + (m0 & 1023) + sh;
#pragma unroll
            for (int j = 0; j < 8; ++j) {
                const int slot = ((sh >> 3) + j) ^ (hdl2 & 15);
                *(float4*)((char*)dst + j*16) = *(const float4*)(smem + hdl2*256 + (slot << 4));
            }
        }
    } else {               // gelu (tanh form) -> bf16
#pragma unroll
        for (int n = 0; n < 4; ++n) {
            const int col = colBase + n*16 + cl;
            const float bv = bias[col];
#pragma unroll
            for (int m = 0; m < 4; ++m) {
#pragma unroll
                for (int i = 0; i < 4; ++i) {
                    const int row = rowBase + m*16 + hi*4 + i;
                    const float v = acc[m][n][i] + bv;
                    const float y = 0.7978845608f * (v + 0.044715f*v*v*v);
                    const float e = __expf(-2.0f * fabsf(y));
                    const float th = (1.0f - e) / (1.0f + e);
                    const float g = 0.5f * v * (1.0f + copysignf(th, y));
                    outb[(size_t)row*N + col] = __float2bfloat16(g);
                }
            }
        }
    }
}

// ---------------- GEMM 64x128, 4 waves: outf += A*Bt^T + bias ----------------
__global__ __launch_bounds__(256)
void gemm64_res_kernel(const __hip_bfloat16* __restrict__ A,
                       const __hip_bfloat16* __restrict__ Bt,
                       const float* __restrict__ bias,
                       float* __restrict__ outf,
                       int N, int K, int nTiles)
{
    __shared__ __hip_bfloat16 As[64*64];
    __shared__ __hip_bfloat16 Bs[128*64];

    const int tid  = threadIdx.x;
    const int lane = tid & 63;
    const int wid  = tid >> 6;

    const int nwg   = gridDim.x;
    const int chunk = nwg >> 3;
    const int bid   = blockIdx.x;
    const int swz   = (bid & 7) * chunk + (bid >> 3);
    const int m0 = (swz / nTiles) * 64;
    const int n0 = (swz % nTiles) * 128;

    const int lrow = lane >> 3;
    const int scol = ((lane & 7) ^ lrow) * 8;
    const __hip_bfloat16* aSrc = A  + (size_t)(m0 + wid*16 + lrow) * K + scol;
    const __hip_bfloat16* bSrc = Bt + (size_t)(n0 + wid*32 + lrow) * K + scol;
    char* aDst = (char*)As + wid*2048 + lane*16;
    char* bDst = (char*)Bs + wid*4096 + lane*16;

    f32x4 acc[2][4] = {};
    const int wm = wid >> 1, wn = wid & 1;
    const int cl = lane & 15, hi = lane >> 4;

    for (int kt = 0; kt < K; kt += 64) {
        __syncthreads();
#pragma unroll
        for (int i = 0; i < 2; ++i)
            gload16(aSrc + kt + (size_t)i*8*K, aDst + i*1024);
#pragma unroll
        for (int i = 0; i < 4; ++i)
            gload16(bSrc + kt + (size_t)i*8*K, bDst + i*1024);
        __syncthreads();

#pragma unroll
        for (int kk = 0; kk < 2; ++kk) {
            bf16x8 af[2], bfr[4];
#pragma unroll
            for (int m = 0; m < 2; ++m) {
                int row  = wm*32 + m*16 + cl;
                int slot = ((kk<<2) + hi) ^ (row & 7);
                af[m] = *(const bf16x8*)((const char*)As + row*128 + slot*16);
            }
#pragma unroll
            for (int n = 0; n < 4; ++n) {
                int row  = wn*64 + n*16 + cl;
                int slot = ((kk<<2) + hi) ^ (row & 7);
                bfr[n] = *(const bf16x8*)((const char*)Bs + row*128 + slot*16);
            }
#pragma unroll
            for (int m = 0; m < 2; ++m)
#pragma unroll
                for (int n = 0; n < 4; ++n)
                    acc[m][n] = __builtin_amdgcn_mfma_f32_16x16x32_bf16(af[m], bfr[n], acc[m][n], 0, 0, 0);
        }
    }

    const int rowBase = m0 + wm*32;
    const int colBase = n0 + wn*64;
#pragma unroll
    for (int n = 0; n < 4; ++n) {
        const int col = colBase + n*16 + cl;
        const float bv = bias[col];
#pragma unroll
        for (int m = 0; m < 2; ++m) {
#pragma unroll
            for (int i = 0; i < 4; ++i) {
                const int row = rowBase + m*16 + hi*4 + i;
                outf[(size_t)row*N + col] += acc[m][n][i] + bv;
            }
        }
    }
}

// ---------------- flash attention, MFMA bf16, 8 waves / 128 q-rows ----------------
// grid = 8*12*8 = 768 blocks = exactly 3 resident blocks/CU (48 KB LDS), no tail.
__global__ __launch_bounds__(512)
void attn_kernel(const __hip_bfloat16* __restrict__ qkb, const __hip_bfloat16* __restrict__ vtb,
                 __hip_bfloat16* __restrict__ attno)
{
    __shared__ __align__(16) char Ks[2][8192];  // [t 64][d 64] bf16, slot^=(t&7)
    __shared__ __align__(16) char Vs[2][8192];  // [d 64][t 64] bf16, slot^=(d&7)
    __shared__ __align__(16) char Ps[16384];    // per-wave P: [q 16][t 64], slot^=(q&7)

    const u16* qk = (const u16*)qkb;
    const u16* vt = (const u16*)vtb;
    const int nwg = gridDim.x, bid = blockIdx.x, chunk = nwg >> 3;
    const int swz = (bid & 7) * chunk + (bid >> 3);
    const int bh = swz >> 3, qb = swz & 7;
    const int b = bh / H_, h = bh % H_;
    const int tid = threadIdx.x;
    const int lane = tid & 63, wid = tid >> 6;   // wid 0..7
    const int cl = lane & 15, hi = lane >> 4;
    const size_t browq = (size_t)(b*S_ + qb*128);

    // Q fragments: q row = wid*16 + cl
    bf16x8 qf[2];
    {
        const u16* qp = qk + (browq + wid*16 + cl)*1536 + h*64;
        qf[0] = *(const bf16x8*)(qp + hi*8);
        qf[1] = *(const bf16x8*)(qp + 32 + hi*8);
    }

    // staging: wave w covers 8 rows (K: t rows, V: d rows); 1 gload each
    const int lrow = lane >> 3;                  // 0..7
    const int scol = ((lane & 7) ^ lrow) * 8;    // swizzled source col
    const u16* kbase = qk + ((size_t)b*S_ + wid*8 + lrow)*1536 + 768 + h*64 + scol;
    const u16* vbase = vt + (((size_t)(b*H_ + h))*64 + wid*8 + lrow)*1024 + scol;
    const int ldst = wid*1024 + lane*16;

    f32x4 acc_o[4] = {};
    float m_run = -1e30f;
    float l_part[4] = {0.f, 0.f, 0.f, 0.f};
    char* pbase = Ps + wid*2048;

    {
        gload16(kbase, Ks[0] + ldst);
        gload16(vbase, Vs[0] + ldst);
    }

    for (int t = 0; t < 16; ++t) {
        __syncthreads();
        if (t < 15) {
            const int nb = (t+1) & 1;
            gload16(kbase + (size_t)(t+1)*64*1536, Ks[nb] + ldst);
            gload16(vbase + (t+1)*64,              Vs[nb] + ldst);
        }
        const char* ks = Ks[t & 1];
        const char* vs = Vs[t & 1];

        // QK^T -> sc[n] (q=hi*4+i, t=n*16+cl)
        f32x4 sc[4] = {};
#pragma unroll
        for (int kk = 0; kk < 2; ++kk) {
            bf16x8 kf[4];
#pragma unroll
            for (int n = 0; n < 4; ++n) {
                const int row = n*16 + cl;
                kf[n] = *(const bf16x8*)(ks + row*128 + (((kk*4 + hi) ^ (cl & 7)) << 4));
            }
#pragma unroll
            for (int n = 0; n < 4; ++n)
                sc[n] = __builtin_amdgcn_mfma_f32_16x16x32_bf16(qf[kk], kf[n], sc[n], 0, 0, 0);
        }

#pragma unroll
        for (int n = 0; n < 4; ++n)
#pragma unroll
            for (int i = 0; i < 4; ++i)
                sc[n][i] *= 0.125f;

        // group max (across this hi group's 4 q-rows) + defer-max
        float gmax = sc[0][0];
#pragma unroll
        for (int n = 0; n < 4; ++n)
#pragma unroll
            for (int i = 0; i < 4; ++i)
                gmax = fmaxf(gmax, sc[n][i]);
        gmax = fmaxf(gmax, __shfl_xor(gmax, 1));
        gmax = fmaxf(gmax, __shfl_xor(gmax, 2));
        gmax = fmaxf(gmax, __shfl_xor(gmax, 4));
        gmax = fmaxf(gmax, __shfl_xor(gmax, 8));
        if (gmax > m_run + 4.0f) {
            const float corr = __expf(m_run - gmax);
            m_run = gmax;
#pragma unroll
            for (int i = 0; i < 4; ++i) l_part[i] *= corr;
#pragma unroll
            for (int nd = 0; nd < 4; ++nd)
#pragma unroll
                for (int i = 0; i < 4; ++i)
                    acc_o[nd][i] *= corr;
        }

        // P = exp(s - m), lane-partial row sums
#pragma unroll
        for (int n = 0; n < 4; ++n) {
#pragma unroll
            for (int i = 0; i < 4; ++i) {
                const float e = __expf(sc[n][i] - m_run);
                l_part[i] += e;
                const int q = hi*4 + i;
                const int slot = (n*2 + (cl >> 3)) ^ (q & 7);
                *(u16*)(pbase + q*128 + slot*16 + (cl & 7)*2) = f2bf_bits(e);
            }
        }

        asm volatile("s_waitcnt lgkmcnt(0)" ::: "memory");
        __builtin_amdgcn_sched_barrier(0);

        // PV: acc_o[nd] += P(frag A) * V^T(frag B)
#pragma unroll
        for (int kk = 0; kk < 2; ++kk) {
            const bf16x8 pf = *(const bf16x8*)(pbase + cl*128 + (((kk*4 + hi) ^ (cl & 7)) << 4));
            bf16x8 vf[4];
#pragma unroll
            for (int nd = 0; nd < 4; ++nd) {
                const int d = nd*16 + cl;
                vf[nd] = *(const bf16x8*)(vs + d*128 + (((kk*4 + hi) ^ (d & 7)) << 4));
            }
#pragma unroll
            for (int nd = 0; nd < 4; ++nd)
                acc_o[nd] = __builtin_amdgcn_mfma_f32_16x16x32_bf16(pf, vf[nd], acc_o[nd], 0, 0, 0);
        }
    }

    u16* op = (u16*)attno;
#pragma unroll
    for (int i = 0; i < 4; ++i) {
        float l = l_part[i];
        l += __shfl_xor(l, 1);
        l += __shfl_xor(l, 2);
        l += __shfl_xor(l, 4);
        l += __shfl_xor(l, 8);
        const float inv = 1.f / l;
        const size_t row = browq + wid*16 + hi*4 + i;
#pragma unroll
        for (int nd = 0; nd < 4; ++nd)
            op[row*768 + h*64 + nd*16 + cl] = f2bf_bits(acc_o[nd][i] * inv);
    }
}

// ---------------- classifier ----------------
__global__ __launch_bounds__(256)
void cls_kernel(const float* __restrict__ x, const float* __restrict__ Wc,
                const float* __restrict__ bc, float* __restrict__ out)
{
    const int b = blockIdx.x;
    const float* xr = x + (size_t)b * S_ * D_;
    float a0 = 0.f, a1 = 0.f;
    for (int d = threadIdx.x; d < 768; d += 256) {
        float xv = xr[d];
        a0 += xv * Wc[d*2+0];
        a1 += xv * Wc[d*2+1];
    }
#pragma unroll
    for (int off = 32; off > 0; off >>= 1) { a0 += __shfl_xor(a0, off); a1 += __shfl_xor(a1, off); }
    __shared__ float r0[4], r1[4];
    const int w = threadIdx.x >> 6;
    if ((threadIdx.x & 63) == 0) { r0[w] = a0; r1[w] = a1; }
    __syncthreads();
    if (threadIdx.x == 0) {
        out[b*2+0] = r0[0]+r0[1]+r0[2]+r0[3] + bc[0];
        out[b*2+1] = r1[0]+r1[1]+r1[2]+r1[3] + bc[1];
    }
}

// ---------------- launch ----------------
extern "C" void kernel_launch(void* const* d_in, const int* in_sizes, int n_in,
                              void* d_out, int out_size, void* d_ws, size_t ws_size,
                              hipStream_t stream)
{
    const int*   tokens  = (const int*)  d_in[0];
    const float* tok_emb = (const float*)d_in[1];
    const float* pos_emb = (const float*)d_in[2];
    const float* e_s     = (const float*)d_in[3];
    const float* e_b     = (const float*)d_in[4];
    const float* Wq      = (const float*)d_in[5];
    const float* bq      = (const float*)d_in[6];
    const float* Wk      = (const float*)d_in[7];
    const float* bk      = (const float*)d_in[8];
    const float* Wv      = (const float*)d_in[9];
    const float* bv      = (const float*)d_in[10];
    const float* Wo      = (const float*)d_in[11];
    const float* bo      = (const float*)d_in[12];
    const float* l1s     = (const float*)d_in[13];
    const float* l1b     = (const float*)d_in[14];
    const float* l2s     = (const float*)d_in[15];
    const float* l2b     = (const float*)d_in[16];
    const float* W1      = (const float*)d_in[17];
    const float* b1      = (const float*)d_in[18];
    const float* W2      = (const float*)d_in[19];
    const float* b2      = (const float*)d_in[20];
    const float* Wc      = (const float*)d_in[21];
    const float* bc      = (const float*)d_in[22];
    (void)in_sizes; (void)n_in; (void)out_size;

    if (ws_size < 102346752) return;   // need ~102.4 MB

    char* ws = (char*)d_ws;
    __hip_bfloat16* wbuf = (__hip_bfloat16*)(ws + 0);          // 14,155,776 B
    float*          bqkv = (float*)(ws + 14155776);            //    110,592 B
    float*          x    = (float*)(ws + 14266368);            // 25,165,824 B
    __hip_bfloat16* xn   = (__hip_bfloat16*)(ws + 39432192);   // 12,582,912 B
    __hip_bfloat16* qk   = (__hip_bfloat16*)(ws + 52015104);   // 25,165,824 B [8192][1536]
    __hip_bfloat16* vT   = (__hip_bfloat16*)(ws + 77180928);   // 12,582,912 B [b*768+hd][1024]
    __hip_bfloat16* att  = (__hip_bfloat16*)(ws + 89763840);   // 12,582,912 B (end 102,346,752)
    __hip_bfloat16* hbuf = qk;                                 // aliases qk+vT+att (50,331,648 B)

    __hip_bfloat16* wqkv_t = wbuf;
    __hip_bfloat16* wo_t   = wbuf + 1769472;
    __hip_bfloat16* w1_t   = wbuf + 2359296;
    __hip_bfloat16* w2_t   = wbuf + 4718592;

    prep_bqkv_kernel<<<108, 256, 0, stream>>>(bq, bk, bv, bqkv);
    embed_ln_kernel<<<2048, 256, 0, stream>>>(tokens, tok_emb, pos_emb, e_s, e_b, x);

    for (int l = 0; l < L_; ++l) {
        prep_layer_kernel<<<1728, 256, 0, stream>>>(Wq, Wk, Wv, Wo, W1, W2, l, wbuf);
        ln_kernel<<<2048, 256, 0, stream>>>(x, l1s + l*768, l1b + l*768, xn);
        gemm_kernel<0><<<1152, 256, 0, stream>>>(xn, wqkv_t, bqkv + l*2304, qk, vT, 2304, 768, 18);
        attn_kernel<<<768, 512, 0, stream>>>(qk, vT, att);
        gemm64_res_kernel<<<768, 256, 0, stream>>>(att, wo_t, bo + l*768, x, 768, 768, 6);
        ln_kernel<<<2048, 256, 0, stream>>>(x, l2s + l*768, l2b + l*768, xn);
        gemm_kernel<1><<<1536, 256, 0, stream>>>(xn, w1_t, b1 + l*3072, hbuf, nullptr, 3072, 768, 24);
        gemm64_res_kernel<<<768, 256, 0, stream>>>(hbuf, w2_t, b2 + l*768, x, 768, 3072, 6);
    }
    cls_kernel<<<8, 256, 0, stream>>>(x, Wc, bc, (float*)d_out);
}

// Round 6
// 3232.278 us; speedup vs baseline: 3.0639x; 1.0028x over previous
//
#include <hip/hip_runtime.h>
#include <hip/hip_bf16.h>
#include <math.h>

// ---------------- constants ----------------
#define B_   8
#define S_   1024
#define D_   768
#define H_   12
#define HD_  64
#define L_   12
#define F_   3072
#define NTOK 8192   // B_*S_

typedef __bf16 bf16x8 __attribute__((ext_vector_type(8)));
typedef float  f32x4  __attribute__((ext_vector_type(4)));
typedef unsigned short u16;

static __device__ __forceinline__ unsigned short f2bf_bits(float f) {
    __hip_bfloat16 h = __float2bfloat16(f);
    return __builtin_bit_cast(unsigned short, h);
}
static __device__ __forceinline__ float bf2f(unsigned short u) {
    unsigned int t = ((unsigned int)u) << 16;
    return __builtin_bit_cast(float, t);
}
static __device__ __forceinline__ void gload16(const void* g, void* l) {
    __builtin_amdgcn_global_load_lds(
        (__attribute__((address_space(1))) void*)g,
        (__attribute__((address_space(3))) void*)l, 16, 0, 0);
}

// ---------------- weight prep: fp32 [R][C] -> bf16 transposed [C][R] ----------------
// vectorized: float4 loads, LDS transpose, ushort4 stores
__global__ __launch_bounds__(256)
void prep_layer_kernel(const float* __restrict__ Wq, const float* __restrict__ Wk,
                       const float* __restrict__ Wv, const float* __restrict__ Wo,
                       const float* __restrict__ W1, const float* __restrict__ W2,
                       int l, __hip_bfloat16* __restrict__ wbuf)
{
    const int id = blockIdx.x;   // 0..1727
    const float* src; __hip_bfloat16* dst;
    int R, C, r0, c0;
    if (id < 432) {                       // q/k/v heads: src [768][64] per (which,h)
        int dtile = id % 12, t = id / 12; // t = which*12 + h
        int which = t / 12, h = t % 12;
        src = (which == 0 ? Wq : which == 1 ? Wk : Wv) + (size_t)(l*12 + h) * 768 * 64;
        dst = wbuf + (size_t)(which*768 + h*64) * 768;
        R = 768; C = 64; r0 = dtile * 64; c0 = 0;
    } else if (id < 576) {                // Wo: [768][768]
        int t = id - 432;
        src = Wo + (size_t)l * 768 * 768;
        dst = wbuf + 1769472;
        R = 768; C = 768; r0 = (t / 12) * 64; c0 = (t % 12) * 64;
    } else if (id < 1152) {               // W1: [768][3072]
        int t = id - 576;
        src = W1 + (size_t)l * 768 * 3072;
        dst = wbuf + 2359296;
        R = 768; C = 3072; r0 = (t % 12) * 64; c0 = (t / 12) * 64;
    } else {                              // W2: [3072][768]
        int t = id - 1152;
        src = W2 + (size_t)l * 3072 * 768;
        dst = wbuf + 4718592;
        R = 3072; C = 768; r0 = (t / 12) * 64; c0 = (t % 12) * 64;
    }
    __shared__ u16 T[64][68];             // transposed bf16 tile, padded
    const int t = threadIdx.x;
    const int row = t >> 2, part = t & 3;
#pragma unroll
    for (int j = 0; j < 4; ++j) {
        const int c4 = (part + j*4) * 4;
        float4 v = *(const float4*)(src + (size_t)(r0 + row) * C + c0 + c4);
        T[c4+0][row] = f2bf_bits(v.x);
        T[c4+1][row] = f2bf_bits(v.y);
        T[c4+2][row] = f2bf_bits(v.z);
        T[c4+3][row] = f2bf_bits(v.w);
    }
    __syncthreads();
    const int c = t >> 2;
    u16* drow = (u16*)dst + (size_t)(c0 + c) * R + r0;
#pragma unroll
    for (int j = 0; j < 4; ++j) {
        const int r4 = (part + j*4) * 4;
        ushort4 pk = *(const ushort4*)&T[c][r4];
        *(ushort4*)(drow + r4) = pk;
    }
}

__global__ __launch_bounds__(256)
void prep_bqkv_kernel(const float* __restrict__ bq, const float* __restrict__ bk,
                      const float* __restrict__ bv, float* __restrict__ bqkv)
{
    int i = blockIdx.x * 256 + threadIdx.x;   // < 12*2304
    int l = i / 2304, c = i % 2304;
    int which = c / 768, hk = c % 768;
    const float* src = which == 0 ? bq : which == 1 ? bk : bv;
    bqkv[i] = src[l*768 + hk];
}

// ---------------- embedding + LN -> x (fp32) ----------------
__global__ __launch_bounds__(256)
void embed_ln_kernel(const int* __restrict__ tokens, const float* __restrict__ tok_emb,
                     const float* __restrict__ pos_emb, const float* __restrict__ gam,
                     const float* __restrict__ bet, float* __restrict__ x)
{
    const int row  = blockIdx.x*4 + (threadIdx.x >> 6);
    const int lane = threadIdx.x & 63;
    const int s    = row & (S_-1);
    const int tok  = tokens[row];
    const float* te = tok_emb + (size_t)tok * D_;
    const float* pe = pos_emb + (size_t)s   * D_;
    float v[12]; float s1 = 0.f, s2 = 0.f;
#pragma unroll
    for (int c = 0; c < 3; ++c) {
        const int base = c*256 + lane*4;
        float4 a = *(const float4*)(te + base);
        float4 p = *(const float4*)(pe + base);
        float t0 = a.x+p.x, t1 = a.y+p.y, t2 = a.z+p.z, t3 = a.w+p.w;
        v[c*4+0]=t0; v[c*4+1]=t1; v[c*4+2]=t2; v[c*4+3]=t3;
        s1 += t0+t1+t2+t3;
        s2 += t0*t0 + t1*t1 + t2*t2 + t3*t3;
    }
#pragma unroll
    for (int off = 32; off > 0; off >>= 1) { s1 += __shfl_xor(s1, off); s2 += __shfl_xor(s2, off); }
    const float mean = s1 * (1.f/768.f);
    const float rstd = rsqrtf(s2*(1.f/768.f) - mean*mean + 1e-5f);
    float* xr = x + (size_t)row * D_;
#pragma unroll
    for (int c = 0; c < 3; ++c) {
        const int base = c*256 + lane*4;
        float4 g = *(const float4*)(gam + base);
        float4 bb = *(const float4*)(bet + base);
        float4 o;
        o.x = (v[c*4+0]-mean)*rstd*g.x + bb.x;
        o.y = (v[c*4+1]-mean)*rstd*g.y + bb.y;
        o.z = (v[c*4+2]-mean)*rstd*g.z + bb.z;
        o.w = (v[c*4+3]-mean)*rstd*g.w + bb.w;
        *(float4*)(xr + base) = o;
    }
}

// ---------------- LN: x (fp32) -> xn (bf16) ----------------
__global__ __launch_bounds__(256)
void ln_kernel(const float* __restrict__ xin, const float* __restrict__ gam,
               const float* __restrict__ bet, __hip_bfloat16* __restrict__ out)
{
    const int row  = blockIdx.x*4 + (threadIdx.x >> 6);
    const int lane = threadIdx.x & 63;
    const float* xr = xin + (size_t)row * D_;
    float v[12]; float s1 = 0.f, s2 = 0.f;
#pragma unroll
    for (int c = 0; c < 3; ++c) {
        float4 t = *(const float4*)(xr + c*256 + lane*4);
        v[c*4+0]=t.x; v[c*4+1]=t.y; v[c*4+2]=t.z; v[c*4+3]=t.w;
        s1 += t.x+t.y+t.z+t.w;
        s2 += t.x*t.x + t.y*t.y + t.z*t.z + t.w*t.w;
    }
#pragma unroll
    for (int off = 32; off > 0; off >>= 1) { s1 += __shfl_xor(s1, off); s2 += __shfl_xor(s2, off); }
    const float mean = s1 * (1.f/768.f);
    const float rstd = rsqrtf(s2*(1.f/768.f) - mean*mean + 1e-5f);
    unsigned short* op = (unsigned short*)out + (size_t)row * D_;
#pragma unroll
    for (int c = 0; c < 3; ++c) {
        const int base = c*256 + lane*4;
        float4 g = *(const float4*)(gam + base);
        float4 bb = *(const float4*)(bet + base);
        ushort4 pk;
        pk.x = f2bf_bits((v[c*4+0]-mean)*rstd*g.x + bb.x);
        pk.y = f2bf_bits((v[c*4+1]-mean)*rstd*g.y + bb.y);
        pk.z = f2bf_bits((v[c*4+2]-mean)*rstd*g.z + bb.z);
        pk.w = f2bf_bits((v[c*4+3]-mean)*rstd*g.w + bb.w);
        *(ushort4*)(op + base) = pk;
    }
}

// ---------------- GEMM 128x128: C = A * Bt^T + bias ----------------
// EPI 0: QKV — Q/K cols -> outb (stride 1536) via LDS repack; V cols -> V^T via LDS transpose
// EPI 1: gelu(tanh) -> bf16 (stride N) via LDS repack
template<int EPI>
__global__ __launch_bounds__(256)
void gemm_kernel(const __hip_bfloat16* __restrict__ A,
                 const __hip_bfloat16* __restrict__ Bt,
                 const float* __restrict__ bias,
                 __hip_bfloat16* __restrict__ outb,
                 __hip_bfloat16* __restrict__ outv,
                 int N, int K, int nTiles)
{
    __shared__ __align__(16) char smem[32768];
    __hip_bfloat16* As = (__hip_bfloat16*)smem;
    __hip_bfloat16* Bs = (__hip_bfloat16*)(smem + 16384);

    const int tid  = threadIdx.x;
    const int lane = tid & 63;
    const int wid  = tid >> 6;

    const int nwg   = gridDim.x;
    const int chunk = nwg >> 3;
    const int bid   = blockIdx.x;
    const int swz   = (bid & 7) * chunk + (bid >> 3);
    const int m0 = (swz / nTiles) * 128;
    const int n0 = (swz % nTiles) * 128;

    const int srow = wid*32 + (lane >> 3);
    const int scol = ((lane & 7) ^ (srow & 7)) * 8;
    const __hip_bfloat16* aSrc = A  + (size_t)(m0 + srow) * K + scol;
    const __hip_bfloat16* bSrc = Bt + (size_t)(n0 + srow) * K + scol;
    char* aDst = (char*)As + wid*4096 + lane*16;
    char* bDst = (char*)Bs + wid*4096 + lane*16;

    f32x4 acc[4][4] = {};
    const int wm = wid >> 1, wn = wid & 1;
    const int cl = lane & 15, hi = lane >> 4;

    for (int kt = 0; kt < K; kt += 64) {
        __syncthreads();
#pragma unroll
        for (int i = 0; i < 4; ++i)
            gload16(aSrc + kt + (size_t)i*8*K, aDst + i*1024);
#pragma unroll
        for (int i = 0; i < 4; ++i)
            gload16(bSrc + kt + (size_t)i*8*K, bDst + i*1024);
        __syncthreads();

#pragma unroll
        for (int kk = 0; kk < 2; ++kk) {
            bf16x8 af[4], bfr[4];
#pragma unroll
            for (int m = 0; m < 4; ++m) {
                int row  = wm*64 + m*16 + cl;
                int slot = ((kk<<2) + hi) ^ (row & 7);
                af[m] = *(const bf16x8*)((const char*)As + row*128 + slot*16);
            }
#pragma unroll
            for (int n = 0; n < 4; ++n) {
                int row  = wn*64 + n*16 + cl;
                int slot = ((kk<<2) + hi) ^ (row & 7);
                bfr[n] = *(const bf16x8*)((const char*)Bs + row*128 + slot*16);
            }
#pragma unroll
            for (int m = 0; m < 4; ++m)
#pragma unroll
                for (int n = 0; n < 4; ++n)
                    acc[m][n] = __builtin_amdgcn_mfma_f32_16x16x32_bf16(af[m], bfr[n], acc[m][n], 0, 0, 0);
        }
    }

    const bool vpath = (EPI == 0) && (n0 >= 1536);

    if (!vpath) {
        // ---- bf16 tile repack through LDS -> coalesced float4 stores ----
        // layout: row*256 + ((c8 ^ (row&15))<<4) + (col&7)*2, c8 = col>>3 (tile-local)
        __syncthreads();   // staging LDS dead
#pragma unroll
        for (int n = 0; n < 4; ++n) {
            const int col2 = wn*64 + n*16 + cl;
            const float bv = bias[n0 + col2];
#pragma unroll
            for (int m = 0; m < 4; ++m) {
#pragma unroll
                for (int i = 0; i < 4; ++i) {
                    const int row = wm*64 + m*16 + hi*4 + i;
                    float v = acc[m][n][i] + bv;
                    if constexpr (EPI == 1) {
                        const float y = 0.7978845608f * (v + 0.044715f*v*v*v);
                        const float e = __expf(-2.0f * fabsf(y));
                        const float th = (1.0f - e) / (1.0f + e);
                        v = 0.5f * v * (1.0f + copysignf(th, y));
                    }
                    *(u16*)(smem + row*256 + ((((col2 >> 3) ^ (row & 15))) << 4)
                                 + ((col2 & 7) << 1)) = f2bf_bits(v);
                }
            }
        }
        __syncthreads();
        const int strideN = (EPI == 0) ? 1536 : N;
        const int r  = tid >> 1;
        const int cb = tid & 1;
        char* dst = (char*)outb + ((size_t)(m0 + r) * strideN + n0) * 2;
#pragma unroll
        for (int j = 0; j < 8; ++j) {
            const int ch = cb + j*2;
            float4 vv = *(const float4*)(smem + r*256 + ((ch ^ (r & 15)) << 4));
            *(float4*)(dst + ch*16) = vv;
        }
    } else {
        // V region: transpose 128x128 tile in LDS, store V^T coalesced.
        __syncthreads();   // staging LDS dead
#pragma unroll
        for (int n = 0; n < 4; ++n) {
            const int col = n0 + wn*64 + n*16 + cl;
            const float bv = bias[col];
            const int hdl = wn*64 + n*16 + cl;
#pragma unroll
            for (int m = 0; m < 4; ++m) {
                const int sl = wm*64 + m*16 + hi*4;
                ushort4 pk;
                pk.x = f2bf_bits(acc[m][n][0] + bv);
                pk.y = f2bf_bits(acc[m][n][1] + bv);
                pk.z = f2bf_bits(acc[m][n][2] + bv);
                pk.w = f2bf_bits(acc[m][n][3] + bv);
                *(ushort4*)(smem + hdl*256 + ((((sl >> 3) ^ (hdl & 15))) << 4) + (sl & 7)*2) = pk;
            }
        }
        __syncthreads();
        const int hdl2 = tid >> 1;            // 0..127
        const int sh   = (tid & 1) * 64;      // 0 or 64
        const int hdg  = (n0 - 1536) + hdl2;  // h*64+d
        const int bb   = m0 >> 10;
        u16* dst = (u16*)outv + ((size_t)(bb*768) + hdg)*1024 + (m0 & 1023) + sh;
#pragma unroll
        for (int j = 0; j < 8; ++j) {
            const int slot = ((sh >> 3) + j) ^ (hdl2 & 15);
            *(float4*)((char*)dst + j*16) = *(const float4*)(smem + hdl2*256 + (slot << 4));
        }
    }
}

// ---------------- GEMM 64x128, 4 waves: outf += A*Bt^T + bias ----------------
// fp32 RMW epilogue repacked through LDS -> float4 load/add/store
__global__ __launch_bounds__(256)
void gemm64_res_kernel(const __hip_bfloat16* __restrict__ A,
                       const __hip_bfloat16* __restrict__ Bt,
                       const float* __restrict__ bias,
                       float* __restrict__ outf,
                       int N, int K, int nTiles)
{
    __shared__ __align__(16) char smem[32768];
    __hip_bfloat16* As = (__hip_bfloat16*)smem;            // 8 KB
    __hip_bfloat16* Bs = (__hip_bfloat16*)(smem + 8192);   // 16 KB

    const int tid  = threadIdx.x;
    const int lane = tid & 63;
    const int wid  = tid >> 6;

    const int nwg   = gridDim.x;
    const int chunk = nwg >> 3;
    const int bid   = blockIdx.x;
    const int swz   = (bid & 7) * chunk + (bid >> 3);
    const int m0 = (swz / nTiles) * 64;
    const int n0 = (swz % nTiles) * 128;

    const int lrow = lane >> 3;
    const int scol = ((lane & 7) ^ lrow) * 8;
    const __hip_bfloat16* aSrc = A  + (size_t)(m0 + wid*16 + lrow) * K + scol;
    const __hip_bfloat16* bSrc = Bt + (size_t)(n0 + wid*32 + lrow) * K + scol;
    char* aDst = (char*)As + wid*2048 + lane*16;
    char* bDst = (char*)Bs + wid*4096 + lane*16;

    f32x4 acc[2][4] = {};
    const int wm = wid >> 1, wn = wid & 1;
    const int cl = lane & 15, hi = lane >> 4;

    for (int kt = 0; kt < K; kt += 64) {
        __syncthreads();
#pragma unroll
        for (int i = 0; i < 2; ++i)
            gload16(aSrc + kt + (size_t)i*8*K, aDst + i*1024);
#pragma unroll
        for (int i = 0; i < 4; ++i)
            gload16(bSrc + kt + (size_t)i*8*K, bDst + i*1024);
        __syncthreads();

#pragma unroll
        for (int kk = 0; kk < 2; ++kk) {
            bf16x8 af[2], bfr[4];
#pragma unroll
            for (int m = 0; m < 2; ++m) {
                int row  = wm*32 + m*16 + cl;
                int slot = ((kk<<2) + hi) ^ (row & 7);
                af[m] = *(const bf16x8*)((const char*)As + row*128 + slot*16);
            }
#pragma unroll
            for (int n = 0; n < 4; ++n) {
                int row  = wn*64 + n*16 + cl;
                int slot = ((kk<<2) + hi) ^ (row & 7);
                bfr[n] = *(const bf16x8*)((const char*)Bs + row*128 + slot*16);
            }
#pragma unroll
            for (int m = 0; m < 2; ++m)
#pragma unroll
                for (int n = 0; n < 4; ++n)
                    acc[m][n] = __builtin_amdgcn_mfma_f32_16x16x32_bf16(af[m], bfr[n], acc[m][n], 0, 0, 0);
        }
    }

    // ---- fp32 tile repack: [64 rows][128 cols] f32, slot = (col>>2) ^ (row&31) ----
    __syncthreads();
#pragma unroll
    for (int n = 0; n < 4; ++n) {
        const int col = wn*64 + n*16 + cl;
        const float bv = bias[n0 + col];
#pragma unroll
        for (int m = 0; m < 2; ++m) {
#pragma unroll
            for (int i = 0; i < 4; ++i) {
                const int row = wm*32 + m*16 + hi*4 + i;
                *(float*)(smem + row*512 + ((((col >> 2) ^ (row & 31))) << 4)
                               + ((col & 3) << 2)) = acc[m][n][i] + bv;
            }
        }
    }
    __syncthreads();
    const int r = tid >> 2;
    const int part = tid & 3;
    float* drow = outf + (size_t)(m0 + r) * N + n0;
#pragma unroll
    for (int j = 0; j < 8; ++j) {
        const int ch = part + j*4;
        f32x4 vv = *(const f32x4*)(smem + r*512 + ((ch ^ (r & 31)) << 4));
        float* dp = drow + ch*4;
        f32x4 g = *(const f32x4*)dp;
        g += vv;
        *(f32x4*)dp = g;
    }
}

// ---------------- flash attention, MFMA bf16, 8 waves / 128 q-rows ----------------
__global__ __launch_bounds__(512)
void attn_kernel(const __hip_bfloat16* __restrict__ qkb, const __hip_bfloat16* __restrict__ vtb,
                 __hip_bfloat16* __restrict__ attno)
{
    __shared__ __align__(16) char Ks[2][8192];  // [t 64][d 64] bf16, slot^=(t&7)
    __shared__ __align__(16) char Vs[2][8192];  // [d 64][t 64] bf16, slot^=(d&7)
    __shared__ __align__(16) char Ps[16384];    // per-wave P: [q 16][t 64], slot^=(q&7)

    const u16* qk = (const u16*)qkb;
    const u16* vt = (const u16*)vtb;
    const int nwg = gridDim.x, bid = blockIdx.x, chunk = nwg >> 3;
    const int swz = (bid & 7) * chunk + (bid >> 3);
    const int bh = swz >> 3, qb = swz & 7;
    const int b = bh / H_, h = bh % H_;
    const int tid = threadIdx.x;
    const int lane = tid & 63, wid = tid >> 6;   // wid 0..7
    const int cl = lane & 15, hi = lane >> 4;
    const size_t browq = (size_t)(b*S_ + qb*128);

    bf16x8 qf[2];
    {
        const u16* qp = qk + (browq + wid*16 + cl)*1536 + h*64;
        qf[0] = *(const bf16x8*)(qp + hi*8);
        qf[1] = *(const bf16x8*)(qp + 32 + hi*8);
    }

    const int lrow = lane >> 3;                  // 0..7
    const int scol = ((lane & 7) ^ lrow) * 8;    // swizzled source col
    const u16* kbase = qk + ((size_t)b*S_ + wid*8 + lrow)*1536 + 768 + h*64 + scol;
    const u16* vbase = vt + (((size_t)(b*H_ + h))*64 + wid*8 + lrow)*1024 + scol;
    const int ldst = wid*1024 + lane*16;

    f32x4 acc_o[4] = {};
    float m_run = -1e30f;
    float l_part[4] = {0.f, 0.f, 0.f, 0.f};
    char* pbase = Ps + wid*2048;

    {
        gload16(kbase, Ks[0] + ldst);
        gload16(vbase, Vs[0] + ldst);
    }

    for (int t = 0; t < 16; ++t) {
        __syncthreads();
        if (t < 15) {
            const int nb = (t+1) & 1;
            gload16(kbase + (size_t)(t+1)*64*1536, Ks[nb] + ldst);
            gload16(vbase + (t+1)*64,              Vs[nb] + ldst);
        }
        const char* ks = Ks[t & 1];
        const char* vs = Vs[t & 1];

        f32x4 sc[4] = {};
#pragma unroll
        for (int kk = 0; kk < 2; ++kk) {
            bf16x8 kf[4];
#pragma unroll
            for (int n = 0; n < 4; ++n) {
                const int row = n*16 + cl;
                kf[n] = *(const bf16x8*)(ks + row*128 + (((kk*4 + hi) ^ (cl & 7)) << 4));
            }
#pragma unroll
            for (int n = 0; n < 4; ++n)
                sc[n] = __builtin_amdgcn_mfma_f32_16x16x32_bf16(qf[kk], kf[n], sc[n], 0, 0, 0);
        }

#pragma unroll
        for (int n = 0; n < 4; ++n)
#pragma unroll
            for (int i = 0; i < 4; ++i)
                sc[n][i] *= 0.125f;

        float gmax = sc[0][0];
#pragma unroll
        for (int n = 0; n < 4; ++n)
#pragma unroll
            for (int i = 0; i < 4; ++i)
                gmax = fmaxf(gmax, sc[n][i]);
        gmax = fmaxf(gmax, __shfl_xor(gmax, 1));
        gmax = fmaxf(gmax, __shfl_xor(gmax, 2));
        gmax = fmaxf(gmax, __shfl_xor(gmax, 4));
        gmax = fmaxf(gmax, __shfl_xor(gmax, 8));
        if (gmax > m_run + 4.0f) {
            const float corr = __expf(m_run - gmax);
            m_run = gmax;
#pragma unroll
            for (int i = 0; i < 4; ++i) l_part[i] *= corr;
#pragma unroll
            for (int nd = 0; nd < 4; ++nd)
#pragma unroll
                for (int i = 0; i < 4; ++i)
                    acc_o[nd][i] *= corr;
        }

#pragma unroll
        for (int n = 0; n < 4; ++n) {
#pragma unroll
            for (int i = 0; i < 4; ++i) {
                const float e = __expf(sc[n][i] - m_run);
                l_part[i] += e;
                const int q = hi*4 + i;
                const int slot = (n*2 + (cl >> 3)) ^ (q & 7);
                *(u16*)(pbase + q*128 + slot*16 + (cl & 7)*2) = f2bf_bits(e);
            }
        }

        asm volatile("s_waitcnt lgkmcnt(0)" ::: "memory");
        __builtin_amdgcn_sched_barrier(0);

#pragma unroll
        for (int kk = 0; kk < 2; ++kk) {
            const bf16x8 pf = *(const bf16x8*)(pbase + cl*128 + (((kk*4 + hi) ^ (cl & 7)) << 4));
            bf16x8 vf[4];
#pragma unroll
            for (int nd = 0; nd < 4; ++nd) {
                const int d = nd*16 + cl;
                vf[nd] = *(const bf16x8*)(vs + d*128 + (((kk*4 + hi) ^ (d & 7)) << 4));
            }
#pragma unroll
            for (int nd = 0; nd < 4; ++nd)
                acc_o[nd] = __builtin_amdgcn_mfma_f32_16x16x32_bf16(pf, vf[nd], acc_o[nd], 0, 0, 0);
        }
    }

    u16* op = (u16*)attno;
#pragma unroll
    for (int i = 0; i < 4; ++i) {
        float l = l_part[i];
        l += __shfl_xor(l, 1);
        l += __shfl_xor(l, 2);
        l += __shfl_xor(l, 4);
        l += __shfl_xor(l, 8);
        const float inv = 1.f / l;
        const size_t row = browq + wid*16 + hi*4 + i;
#pragma unroll
        for (int nd = 0; nd < 4; ++nd)
            op[row*768 + h*64 + nd*16 + cl] = f2bf_bits(acc_o[nd][i] * inv);
    }
}

// ---------------- classifier ----------------
__global__ __launch_bounds__(256)
void cls_kernel(const float* __restrict__ x, const float* __restrict__ Wc,
                const float* __restrict__ bc, float* __restrict__ out)
{
    const int b = blockIdx.x;
    const float* xr = x + (size_t)b * S_ * D_;
    float a0 = 0.f, a1 = 0.f;
    for (int d = threadIdx.x; d < 768; d += 256) {
        float xv = xr[d];
        a0 += xv * Wc[d*2+0];
        a1 += xv * Wc[d*2+1];
    }
#pragma unroll
    for (int off = 32; off > 0; off >>= 1) { a0 += __shfl_xor(a0, off); a1 += __shfl_xor(a1, off); }
    __shared__ float r0[4], r1[4];
    const int w = threadIdx.x >> 6;
    if ((threadIdx.x & 63) == 0) { r0[w] = a0; r1[w] = a1; }
    __syncthreads();
    if (threadIdx.x == 0) {
        out[b*2+0] = r0[0]+r0[1]+r0[2]+r0[3] + bc[0];
        out[b*2+1] = r1[0]+r1[1]+r1[2]+r1[3] + bc[1];
    }
}

// ---------------- launch ----------------
extern "C" void kernel_launch(void* const* d_in, const int* in_sizes, int n_in,
                              void* d_out, int out_size, void* d_ws, size_t ws_size,
                              hipStream_t stream)
{
    const int*   tokens  = (const int*)  d_in[0];
    const float* tok_emb = (const float*)d_in[1];
    const float* pos_emb = (const float*)d_in[2];
    const float* e_s     = (const float*)d_in[3];
    const float* e_b     = (const float*)d_in[4];
    const float* Wq      = (const float*)d_in[5];
    const float* bq      = (const float*)d_in[6];
    const float* Wk      = (const float*)d_in[7];
    const float* bk      = (const float*)d_in[8];
    const float* Wv      = (const float*)d_in[9];
    const float* bv      = (const float*)d_in[10];
    const float* Wo      = (const float*)d_in[11];
    const float* bo      = (const float*)d_in[12];
    const float* l1s     = (const float*)d_in[13];
    const float* l1b     = (const float*)d_in[14];
    const float* l2s     = (const float*)d_in[15];
    const float* l2b     = (const float*)d_in[16];
    const float* W1      = (const float*)d_in[17];
    const float* b1      = (const float*)d_in[18];
    const float* W2      = (const float*)d_in[19];
    const float* b2      = (const float*)d_in[20];
    const float* Wc      = (const float*)d_in[21];
    const float* bc      = (const float*)d_in[22];
    (void)in_sizes; (void)n_in; (void)out_size;

    if (ws_size < 102346752) return;   // need ~102.4 MB

    char* ws = (char*)d_ws;
    __hip_bfloat16* wbuf = (__hip_bfloat16*)(ws + 0);          // 14,155,776 B
    float*          bqkv = (float*)(ws + 14155776);            //    110,592 B
    float*          x    = (float*)(ws + 14266368);            // 25,165,824 B
    __hip_bfloat16* xn   = (__hip_bfloat16*)(ws + 39432192);   // 12,582,912 B
    __hip_bfloat16* qk   = (__hip_bfloat16*)(ws + 52015104);   // 25,165,824 B [8192][1536]
    __hip_bfloat16* vT   = (__hip_bfloat16*)(ws + 77180928);   // 12,582,912 B [b*768+hd][1024]
    __hip_bfloat16* att  = (__hip_bfloat16*)(ws + 89763840);   // 12,582,912 B (end 102,346,752)
    __hip_bfloat16* hbuf = qk;                                 // aliases qk+vT+att (50,331,648 B)

    __hip_bfloat16* wqkv_t = wbuf;
    __hip_bfloat16* wo_t   = wbuf + 1769472;
    __hip_bfloat16* w1_t   = wbuf + 2359296;
    __hip_bfloat16* w2_t   = wbuf + 4718592;

    prep_bqkv_kernel<<<108, 256, 0, stream>>>(bq, bk, bv, bqkv);
    embed_ln_kernel<<<2048, 256, 0, stream>>>(tokens, tok_emb, pos_emb, e_s, e_b, x);

    for (int l = 0; l < L_; ++l) {
        prep_layer_kernel<<<1728, 256, 0, stream>>>(Wq, Wk, Wv, Wo, W1, W2, l, wbuf);
        ln_kernel<<<2048, 256, 0, stream>>>(x, l1s + l*768, l1b + l*768, xn);
        gemm_kernel<0><<<1152, 256, 0, stream>>>(xn, wqkv_t, bqkv + l*2304, qk, vT, 2304, 768, 18);
        attn_kernel<<<768, 512, 0, stream>>>(qk, vT, att);
        gemm64_res_kernel<<<768, 256, 0, stream>>>(att, wo_t, bo + l*768, x, 768, 768, 6);
        ln_kernel<<<2048, 256, 0, stream>>>(x, l2s + l*768, l2b + l*768, xn);
        gemm_kernel<1><<<1536, 256, 0, stream>>>(xn, w1_t, b1 + l*3072, hbuf, nullptr, 3072, 768, 24);
        gemm64_res_kernel<<<768, 256, 0, stream>>>(hbuf, w2_t, b2 + l*768, x, 768, 3072, 6);
    }
    cls_kernel<<<8, 256, 0, stream>>>(x, Wc, bc, (float*)d_out);
}

// Round 7
// 3005.403 us; speedup vs baseline: 3.2951x; 1.0755x over previous
//
#include <hip/hip_runtime.h>
#include <hip/hip_bf16.h>
#include <math.h>

// ---------------- constants ----------------
#define B_   8
#define S_   1024
#define D_   768
#define H_   12
#define HD_  64
#define L_   12
#define F_   3072
#define NTOK 8192   // B_*S_

typedef __bf16 bf16x8 __attribute__((ext_vector_type(8)));
typedef float  f32x4  __attribute__((ext_vector_type(4)));
typedef unsigned short u16;

static __device__ __forceinline__ unsigned short f2bf_bits(float f) {
    __hip_bfloat16 h = __float2bfloat16(f);
    return __builtin_bit_cast(unsigned short, h);
}
static __device__ __forceinline__ float bf2f(unsigned short u) {
    unsigned int t = ((unsigned int)u) << 16;
    return __builtin_bit_cast(float, t);
}
static __device__ __forceinline__ void gload16(const void* g, void* l) {
    __builtin_amdgcn_global_load_lds(
        (__attribute__((address_space(1))) void*)g,
        (__attribute__((address_space(3))) void*)l, 16, 0, 0);
}

// ---------------- weight prep: fp32 [R][C] -> bf16 transposed [C][R] ----------------
__global__ __launch_bounds__(256)
void prep_layer_kernel(const float* __restrict__ Wq, const float* __restrict__ Wk,
                       const float* __restrict__ Wv, const float* __restrict__ Wo,
                       const float* __restrict__ W1, const float* __restrict__ W2,
                       int l, __hip_bfloat16* __restrict__ wbuf)
{
    const int id = blockIdx.x;   // 0..1727
    const float* src; __hip_bfloat16* dst;
    int R, C, r0, c0;
    if (id < 432) {                       // q/k/v heads: src [768][64] per (which,h)
        int dtile = id % 12, t = id / 12; // t = which*12 + h
        int which = t / 12, h = t % 12;
        src = (which == 0 ? Wq : which == 1 ? Wk : Wv) + (size_t)(l*12 + h) * 768 * 64;
        dst = wbuf + (size_t)(which*768 + h*64) * 768;
        R = 768; C = 64; r0 = dtile * 64; c0 = 0;
    } else if (id < 576) {                // Wo: [768][768]
        int t = id - 432;
        src = Wo + (size_t)l * 768 * 768;
        dst = wbuf + 1769472;
        R = 768; C = 768; r0 = (t / 12) * 64; c0 = (t % 12) * 64;
    } else if (id < 1152) {               // W1: [768][3072]
        int t = id - 576;
        src = W1 + (size_t)l * 768 * 3072;
        dst = wbuf + 2359296;
        R = 768; C = 3072; r0 = (t % 12) * 64; c0 = (t / 12) * 64;
    } else {                              // W2: [3072][768]
        int t = id - 1152;
        src = W2 + (size_t)l * 3072 * 768;
        dst = wbuf + 4718592;
        R = 3072; C = 768; r0 = (t / 12) * 64; c0 = (t % 12) * 64;
    }
    __shared__ u16 T[64][68];             // transposed bf16 tile, padded
    const int t = threadIdx.x;
    const int row = t >> 2, part = t & 3;
#pragma unroll
    for (int j = 0; j < 4; ++j) {
        const int c4 = (part + j*4) * 4;
        float4 v = *(const float4*)(src + (size_t)(r0 + row) * C + c0 + c4);
        T[c4+0][row] = f2bf_bits(v.x);
        T[c4+1][row] = f2bf_bits(v.y);
        T[c4+2][row] = f2bf_bits(v.z);
        T[c4+3][row] = f2bf_bits(v.w);
    }
    __syncthreads();
    const int c = t >> 2;
    u16* drow = (u16*)dst + (size_t)(c0 + c) * R + r0;
#pragma unroll
    for (int j = 0; j < 4; ++j) {
        const int r4 = (part + j*4) * 4;
        ushort4 pk = *(const ushort4*)&T[c][r4];
        *(ushort4*)(drow + r4) = pk;
    }
}

__global__ __launch_bounds__(256)
void prep_bqkv_kernel(const float* __restrict__ bq, const float* __restrict__ bk,
                      const float* __restrict__ bv, float* __restrict__ bqkv)
{
    int i = blockIdx.x * 256 + threadIdx.x;   // < 12*2304
    int l = i / 2304, c = i % 2304;
    int which = c / 768, hk = c % 768;
    const float* src = which == 0 ? bq : which == 1 ? bk : bv;
    bqkv[i] = src[l*768 + hk];
}

// ---------------- embedding + LN -> x (fp32) ----------------
__global__ __launch_bounds__(256)
void embed_ln_kernel(const int* __restrict__ tokens, const float* __restrict__ tok_emb,
                     const float* __restrict__ pos_emb, const float* __restrict__ gam,
                     const float* __restrict__ bet, float* __restrict__ x)
{
    const int row  = blockIdx.x*4 + (threadIdx.x >> 6);
    const int lane = threadIdx.x & 63;
    const int s    = row & (S_-1);
    const int tok  = tokens[row];
    const float* te = tok_emb + (size_t)tok * D_;
    const float* pe = pos_emb + (size_t)s   * D_;
    float v[12]; float s1 = 0.f, s2 = 0.f;
#pragma unroll
    for (int c = 0; c < 3; ++c) {
        const int base = c*256 + lane*4;
        float4 a = *(const float4*)(te + base);
        float4 p = *(const float4*)(pe + base);
        float t0 = a.x+p.x, t1 = a.y+p.y, t2 = a.z+p.z, t3 = a.w+p.w;
        v[c*4+0]=t0; v[c*4+1]=t1; v[c*4+2]=t2; v[c*4+3]=t3;
        s1 += t0+t1+t2+t3;
        s2 += t0*t0 + t1*t1 + t2*t2 + t3*t3;
    }
#pragma unroll
    for (int off = 32; off > 0; off >>= 1) { s1 += __shfl_xor(s1, off); s2 += __shfl_xor(s2, off); }
    const float mean = s1 * (1.f/768.f);
    const float rstd = rsqrtf(s2*(1.f/768.f) - mean*mean + 1e-5f);
    float* xr = x + (size_t)row * D_;
#pragma unroll
    for (int c = 0; c < 3; ++c) {
        const int base = c*256 + lane*4;
        float4 g = *(const float4*)(gam + base);
        float4 bb = *(const float4*)(bet + base);
        float4 o;
        o.x = (v[c*4+0]-mean)*rstd*g.x + bb.x;
        o.y = (v[c*4+1]-mean)*rstd*g.y + bb.y;
        o.z = (v[c*4+2]-mean)*rstd*g.z + bb.z;
        o.w = (v[c*4+3]-mean)*rstd*g.w + bb.w;
        *(float4*)(xr + base) = o;
    }
}

// ---------------- LN: x (fp32) -> xn (bf16) ----------------
__global__ __launch_bounds__(256)
void ln_kernel(const float* __restrict__ xin, const float* __restrict__ gam,
               const float* __restrict__ bet, __hip_bfloat16* __restrict__ out)
{
    const int row  = blockIdx.x*4 + (threadIdx.x >> 6);
    const int lane = threadIdx.x & 63;
    const float* xr = xin + (size_t)row * D_;
    float v[12]; float s1 = 0.f, s2 = 0.f;
#pragma unroll
    for (int c = 0; c < 3; ++c) {
        float4 t = *(const float4*)(xr + c*256 + lane*4);
        v[c*4+0]=t.x; v[c*4+1]=t.y; v[c*4+2]=t.z; v[c*4+3]=t.w;
        s1 += t.x+t.y+t.z+t.w;
        s2 += t.x*t.x + t.y*t.y + t.z*t.z + t.w*t.w;
    }
#pragma unroll
    for (int off = 32; off > 0; off >>= 1) { s1 += __shfl_xor(s1, off); s2 += __shfl_xor(s2, off); }
    const float mean = s1 * (1.f/768.f);
    const float rstd = rsqrtf(s2*(1.f/768.f) - mean*mean + 1e-5f);
    unsigned short* op = (unsigned short*)out + (size_t)row * D_;
#pragma unroll
    for (int c = 0; c < 3; ++c) {
        const int base = c*256 + lane*4;
        float4 g = *(const float4*)(gam + base);
        float4 bb = *(const float4*)(bet + base);
        ushort4 pk;
        pk.x = f2bf_bits((v[c*4+0]-mean)*rstd*g.x + bb.x);
        pk.y = f2bf_bits((v[c*4+1]-mean)*rstd*g.y + bb.y);
        pk.z = f2bf_bits((v[c*4+2]-mean)*rstd*g.z + bb.z);
        pk.w = f2bf_bits((v[c*4+3]-mean)*rstd*g.w + bb.w);
        *(ushort4*)(op + base) = pk;
    }
}

// ---------------- unified GEMM 64x128, 4 waves, DOUBLE-BUFFERED staging ----------------
// C[64,128] = A[M,K] * Bt[N,K]^T + bias. One barrier per K-step; tile t+1 loads
// issued before computing tile t (loads fly under MFMA+ds_read).
// EPI 0: QKV — n0<1536: Q/K -> outb stride 1536; else V -> outv = V^T [(b*768+hd)][1024]
// EPI 1: gelu(tanh) -> outb stride N
// EPI 2: outf += acc + bias (fp32 residual RMW)
template<int EPI>
__global__ __launch_bounds__(256)
void gemm_kernel(const __hip_bfloat16* __restrict__ A,
                 const __hip_bfloat16* __restrict__ Bt,
                 const float* __restrict__ bias,
                 __hip_bfloat16* __restrict__ outb,
                 __hip_bfloat16* __restrict__ outv,
                 float* __restrict__ outf,
                 int N, int K, int nTiles)
{
    __shared__ __align__(16) char smem[49152];
    char* const As0 = smem;            // 8 KB
    char* const As1 = smem + 8192;     // 8 KB
    char* const Bs0 = smem + 16384;    // 16 KB
    char* const Bs1 = smem + 32768;    // 16 KB

    const int tid  = threadIdx.x;
    const int lane = tid & 63;
    const int wid  = tid >> 6;

    const int nwg   = gridDim.x;
    const int chunk = nwg >> 3;
    const int bid   = blockIdx.x;
    const int swz   = (bid & 7) * chunk + (bid >> 3);
    const int m0 = (swz / nTiles) * 64;
    const int n0 = (swz % nTiles) * 128;

    const int lrow = lane >> 3;                 // 0..7
    const int scol = ((lane & 7) ^ lrow) * 8;   // swizzled source col
    const __hip_bfloat16* aSrc = A  + (size_t)(m0 + wid*16 + lrow) * K + scol;
    const __hip_bfloat16* bSrc = Bt + (size_t)(n0 + wid*32 + lrow) * K + scol;
    const int aOff = wid*2048 + lane*16;
    const int bOff = wid*4096 + lane*16;

    f32x4 acc[2][4] = {};
    const int wm = wid >> 1, wn = wid & 1;
    const int cl = lane & 15, hi = lane >> 4;

    // prologue: stage tile 0 into buf0
#pragma unroll
    for (int i = 0; i < 2; ++i)
        gload16(aSrc + (size_t)i*8*K, As0 + aOff + i*1024);
#pragma unroll
    for (int i = 0; i < 4; ++i)
        gload16(bSrc + (size_t)i*8*K, Bs0 + bOff + i*1024);

    int buf = 0;
    for (int kt = 0; kt < K; kt += 64, buf ^= 1) {
        __syncthreads();   // drains vmcnt -> buf[cur] ready; orders prior reads
        if (kt + 64 < K) { // prefetch next tile into the other buffer
            char* an = buf ? As0 : As1;
            char* bn = buf ? Bs0 : Bs1;
#pragma unroll
            for (int i = 0; i < 2; ++i)
                gload16(aSrc + kt + 64 + (size_t)i*8*K, an + aOff + i*1024);
#pragma unroll
            for (int i = 0; i < 4; ++i)
                gload16(bSrc + kt + 64 + (size_t)i*8*K, bn + bOff + i*1024);
        }
        const char* ac = buf ? As1 : As0;
        const char* bc = buf ? Bs1 : Bs0;

#pragma unroll
        for (int kk = 0; kk < 2; ++kk) {
            bf16x8 af[2], bfr[4];
#pragma unroll
            for (int m = 0; m < 2; ++m) {
                int row  = wm*32 + m*16 + cl;
                int slot = ((kk<<2) + hi) ^ (row & 7);
                af[m] = *(const bf16x8*)(ac + row*128 + slot*16);
            }
#pragma unroll
            for (int n = 0; n < 4; ++n) {
                int row  = wn*64 + n*16 + cl;
                int slot = ((kk<<2) + hi) ^ (row & 7);
                bfr[n] = *(const bf16x8*)(bc + row*128 + slot*16);
            }
#pragma unroll
            for (int m = 0; m < 2; ++m)
#pragma unroll
                for (int n = 0; n < 4; ++n)
                    acc[m][n] = __builtin_amdgcn_mfma_f32_16x16x32_bf16(af[m], bfr[n], acc[m][n], 0, 0, 0);
        }
    }

    __syncthreads();   // staging LDS dead; safe to reuse for epilogue repack

    const bool vpath = (EPI == 0) && (n0 >= 1536);

    if constexpr (EPI == 2) {
        // fp32 tile repack: [64 rows][128 cols] f32, slot = (col>>2) ^ (row&31)
#pragma unroll
        for (int n = 0; n < 4; ++n) {
            const int col = wn*64 + n*16 + cl;
            const float bv = bias[n0 + col];
#pragma unroll
            for (int m = 0; m < 2; ++m) {
#pragma unroll
                for (int i = 0; i < 4; ++i) {
                    const int row = wm*32 + m*16 + hi*4 + i;
                    *(float*)(smem + row*512 + ((((col >> 2) ^ (row & 31))) << 4)
                                   + ((col & 3) << 2)) = acc[m][n][i] + bv;
                }
            }
        }
        __syncthreads();
        const int r = tid >> 2;
        const int part = tid & 3;
        float* drow = outf + (size_t)(m0 + r) * N + n0;
#pragma unroll
        for (int j = 0; j < 8; ++j) {
            const int ch = part + j*4;
            f32x4 vv = *(const f32x4*)(smem + r*512 + ((ch ^ (r & 31)) << 4));
            float* dp = drow + ch*4;
            f32x4 g = *(const f32x4*)dp;
            g += vv;
            *(f32x4*)dp = g;
        }
    } else if (!vpath) {
        // bf16 tile repack: [64 rows][128 cols], slot = (col>>3) ^ (row&15)
#pragma unroll
        for (int n = 0; n < 4; ++n) {
            const int col2 = wn*64 + n*16 + cl;
            const float bv = bias[n0 + col2];
#pragma unroll
            for (int m = 0; m < 2; ++m) {
#pragma unroll
                for (int i = 0; i < 4; ++i) {
                    const int row = wm*32 + m*16 + hi*4 + i;
                    float v = acc[m][n][i] + bv;
                    if constexpr (EPI == 1) {
                        const float y = 0.7978845608f * (v + 0.044715f*v*v*v);
                        const float e = __expf(-2.0f * fabsf(y));
                        const float th = (1.0f - e) / (1.0f + e);
                        v = 0.5f * v * (1.0f + copysignf(th, y));
                    }
                    *(u16*)(smem + row*256 + ((((col2 >> 3) ^ (row & 15))) << 4)
                                 + ((col2 & 7) << 1)) = f2bf_bits(v);
                }
            }
        }
        __syncthreads();
        const int strideN = (EPI == 0) ? 1536 : N;
        const int r  = tid >> 2;
        const int part = tid & 3;
        u16* dst = (u16*)outb + (size_t)(m0 + r) * strideN + n0;
#pragma unroll
        for (int j = 0; j < 4; ++j) {
            const int ch = part + j*4;
            float4 vv = *(const float4*)(smem + r*256 + ((ch ^ (r & 15)) << 4));
            *(float4*)((char*)dst + ch*16) = vv;
        }
    } else {
        // V region: transpose [s 64][hd 128] tile in LDS -> V^T coalesced stores.
        // layout: hd*128 + ((s>>3 ^ (hd&7))<<4) + (s&7)*2
#pragma unroll
        for (int n = 0; n < 4; ++n) {
            const int hdl = wn*64 + n*16 + cl;
            const float bv = bias[n0 + hdl];
#pragma unroll
            for (int m = 0; m < 2; ++m) {
                const int sl = wm*32 + m*16 + hi*4;
                ushort4 pk;
                pk.x = f2bf_bits(acc[m][n][0] + bv);
                pk.y = f2bf_bits(acc[m][n][1] + bv);
                pk.z = f2bf_bits(acc[m][n][2] + bv);
                pk.w = f2bf_bits(acc[m][n][3] + bv);
                *(ushort4*)(smem + hdl*128 + ((((sl >> 3) ^ (hdl & 7))) << 4) + (sl & 7)*2) = pk;
            }
        }
        __syncthreads();
        const int hdl2 = tid >> 1;            // 0..127
        const int sh   = (tid & 1) * 32;      // s offset 0 or 32
        const int hdg  = (n0 - 1536) + hdl2;  // h*64+d
        const int bb   = m0 >> 10;
        u16* dst = (u16*)outv + ((size_t)(bb*768) + hdg)*1024 + (m0 & 1023) + sh;
#pragma unroll
        for (int j = 0; j < 4; ++j) {
            const int slot = ((sh >> 3) + j) ^ (hdl2 & 7);
            *(float4*)((char*)dst + j*16) = *(const float4*)(smem + hdl2*128 + (slot << 4));
        }
    }
}

// ---------------- flash attention, MFMA bf16, 8 waves / 128 q-rows ----------------
__global__ __launch_bounds__(512)
void attn_kernel(const __hip_bfloat16* __restrict__ qkb, const __hip_bfloat16* __restrict__ vtb,
                 __hip_bfloat16* __restrict__ attno)
{
    __shared__ __align__(16) char Ks[2][8192];  // [t 64][d 64] bf16, slot^=(t&7)
    __shared__ __align__(16) char Vs[2][8192];  // [d 64][t 64] bf16, slot^=(d&7)
    __shared__ __align__(16) char Ps[16384];    // per-wave P: [q 16][t 64], slot^=(q&7)

    const u16* qk = (const u16*)qkb;
    const u16* vt = (const u16*)vtb;
    const int nwg = gridDim.x, bid = blockIdx.x, chunk = nwg >> 3;
    const int swz = (bid & 7) * chunk + (bid >> 3);
    const int bh = swz >> 3, qb = swz & 7;
    const int b = bh / H_, h = bh % H_;
    const int tid = threadIdx.x;
    const int lane = tid & 63, wid = tid >> 6;   // wid 0..7
    const int cl = lane & 15, hi = lane >> 4;
    const size_t browq = (size_t)(b*S_ + qb*128);

    bf16x8 qf[2];
    {
        const u16* qp = qk + (browq + wid*16 + cl)*1536 + h*64;
        qf[0] = *(const bf16x8*)(qp + hi*8);
        qf[1] = *(const bf16x8*)(qp + 32 + hi*8);
    }

    const int lrow = lane >> 3;                  // 0..7
    const int scol = ((lane & 7) ^ lrow) * 8;    // swizzled source col
    const u16* kbase = qk + ((size_t)b*S_ + wid*8 + lrow)*1536 + 768 + h*64 + scol;
    const u16* vbase = vt + (((size_t)(b*H_ + h))*64 + wid*8 + lrow)*1024 + scol;
    const int ldst = wid*1024 + lane*16;

    f32x4 acc_o[4] = {};
    float m_run = -1e30f;
    float l_part[4] = {0.f, 0.f, 0.f, 0.f};
    char* pbase = Ps + wid*2048;

    {
        gload16(kbase, Ks[0] + ldst);
        gload16(vbase, Vs[0] + ldst);
    }

    for (int t = 0; t < 16; ++t) {
        __syncthreads();
        if (t < 15) {
            const int nb = (t+1) & 1;
            gload16(kbase + (size_t)(t+1)*64*1536, Ks[nb] + ldst);
            gload16(vbase + (t+1)*64,              Vs[nb] + ldst);
        }
        const char* ks = Ks[t & 1];
        const char* vs = Vs[t & 1];

        f32x4 sc[4] = {};
#pragma unroll
        for (int kk = 0; kk < 2; ++kk) {
            bf16x8 kf[4];
#pragma unroll
            for (int n = 0; n < 4; ++n) {
                const int row = n*16 + cl;
                kf[n] = *(const bf16x8*)(ks + row*128 + (((kk*4 + hi) ^ (cl & 7)) << 4));
            }
#pragma unroll
            for (int n = 0; n < 4; ++n)
                sc[n] = __builtin_amdgcn_mfma_f32_16x16x32_bf16(qf[kk], kf[n], sc[n], 0, 0, 0);
        }

#pragma unroll
        for (int n = 0; n < 4; ++n)
#pragma unroll
            for (int i = 0; i < 4; ++i)
                sc[n][i] *= 0.125f;

        float gmax = sc[0][0];
#pragma unroll
        for (int n = 0; n < 4; ++n)
#pragma unroll
            for (int i = 0; i < 4; ++i)
                gmax = fmaxf(gmax, sc[n][i]);
        gmax = fmaxf(gmax, __shfl_xor(gmax, 1));
        gmax = fmaxf(gmax, __shfl_xor(gmax, 2));
        gmax = fmaxf(gmax, __shfl_xor(gmax, 4));
        gmax = fmaxf(gmax, __shfl_xor(gmax, 8));
        if (gmax > m_run + 4.0f) {
            const float corr = __expf(m_run - gmax);
            m_run = gmax;
#pragma unroll
            for (int i = 0; i < 4; ++i) l_part[i] *= corr;
#pragma unroll
            for (int nd = 0; nd < 4; ++nd)
#pragma unroll
                for (int i = 0; i < 4; ++i)
                    acc_o[nd][i] *= corr;
        }

#pragma unroll
        for (int n = 0; n < 4; ++n) {
#pragma unroll
            for (int i = 0; i < 4; ++i) {
                const float e = __expf(sc[n][i] - m_run);
                l_part[i] += e;
                const int q = hi*4 + i;
                const int slot = (n*2 + (cl >> 3)) ^ (q & 7);
                *(u16*)(pbase + q*128 + slot*16 + (cl & 7)*2) = f2bf_bits(e);
            }
        }

        asm volatile("s_waitcnt lgkmcnt(0)" ::: "memory");
        __builtin_amdgcn_sched_barrier(0);

#pragma unroll
        for (int kk = 0; kk < 2; ++kk) {
            const bf16x8 pf = *(const bf16x8*)(pbase + cl*128 + (((kk*4 + hi) ^ (cl & 7)) << 4));
            bf16x8 vf[4];
#pragma unroll
            for (int nd = 0; nd < 4; ++nd) {
                const int d = nd*16 + cl;
                vf[nd] = *(const bf16x8*)(vs + d*128 + (((kk*4 + hi) ^ (d & 7)) << 4));
            }
#pragma unroll
            for (int nd = 0; nd < 4; ++nd)
                acc_o[nd] = __builtin_amdgcn_mfma_f32_16x16x32_bf16(pf, vf[nd], acc_o[nd], 0, 0, 0);
        }
    }

    u16* op = (u16*)attno;
#pragma unroll
    for (int i = 0; i < 4; ++i) {
        float l = l_part[i];
        l += __shfl_xor(l, 1);
        l += __shfl_xor(l, 2);
        l += __shfl_xor(l, 4);
        l += __shfl_xor(l, 8);
        const float inv = 1.f / l;
        const size_t row = browq + wid*16 + hi*4 + i;
#pragma unroll
        for (int nd = 0; nd < 4; ++nd)
            op[row*768 + h*64 + nd*16 + cl] = f2bf_bits(acc_o[nd][i] * inv);
    }
}

// ---------------- classifier ----------------
__global__ __launch_bounds__(256)
void cls_kernel(const float* __restrict__ x, const float* __restrict__ Wc,
                const float* __restrict__ bc, float* __restrict__ out)
{
    const int b = blockIdx.x;
    const float* xr = x + (size_t)b * S_ * D_;
    float a0 = 0.f, a1 = 0.f;
    for (int d = threadIdx.x; d < 768; d += 256) {
        float xv = xr[d];
        a0 += xv * Wc[d*2+0];
        a1 += xv * Wc[d*2+1];
    }
#pragma unroll
    for (int off = 32; off > 0; off >>= 1) { a0 += __shfl_xor(a0, off); a1 += __shfl_xor(a1, off); }
    __shared__ float r0[4], r1[4];
    const int w = threadIdx.x >> 6;
    if ((threadIdx.x & 63) == 0) { r0[w] = a0; r1[w] = a1; }
    __syncthreads();
    if (threadIdx.x == 0) {
        out[b*2+0] = r0[0]+r0[1]+r0[2]+r0[3] + bc[0];
        out[b*2+1] = r1[0]+r1[1]+r1[2]+r1[3] + bc[1];
    }
}

// ---------------- launch ----------------
extern "C" void kernel_launch(void* const* d_in, const int* in_sizes, int n_in,
                              void* d_out, int out_size, void* d_ws, size_t ws_size,
                              hipStream_t stream)
{
    const int*   tokens  = (const int*)  d_in[0];
    const float* tok_emb = (const float*)d_in[1];
    const float* pos_emb = (const float*)d_in[2];
    const float* e_s     = (const float*)d_in[3];
    const float* e_b     = (const float*)d_in[4];
    const float* Wq      = (const float*)d_in[5];
    const float* bq      = (const float*)d_in[6];
    const float* Wk      = (const float*)d_in[7];
    const float* bk      = (const float*)d_in[8];
    const float* Wv      = (const float*)d_in[9];
    const float* bv      = (const float*)d_in[10];
    const float* Wo      = (const float*)d_in[11];
    const float* bo      = (const float*)d_in[12];
    const float* l1s     = (const float*)d_in[13];
    const float* l1b     = (const float*)d_in[14];
    const float* l2s     = (const float*)d_in[15];
    const float* l2b     = (const float*)d_in[16];
    const float* W1      = (const float*)d_in[17];
    const float* b1      = (const float*)d_in[18];
    const float* W2      = (const float*)d_in[19];
    const float* b2      = (const float*)d_in[20];
    const float* Wc      = (const float*)d_in[21];
    const float* bc      = (const float*)d_in[22];
    (void)in_sizes; (void)n_in; (void)out_size;

    if (ws_size < 102346752) return;   // need ~102.4 MB

    char* ws = (char*)d_ws;
    __hip_bfloat16* wbuf = (__hip_bfloat16*)(ws + 0);          // 14,155,776 B
    float*          bqkv = (float*)(ws + 14155776);            //    110,592 B
    float*          x    = (float*)(ws + 14266368);            // 25,165,824 B
    __hip_bfloat16* xn   = (__hip_bfloat16*)(ws + 39432192);   // 12,582,912 B
    __hip_bfloat16* qk   = (__hip_bfloat16*)(ws + 52015104);   // 25,165,824 B [8192][1536]
    __hip_bfloat16* vT   = (__hip_bfloat16*)(ws + 77180928);   // 12,582,912 B [b*768+hd][1024]
    __hip_bfloat16* att  = (__hip_bfloat16*)(ws + 89763840);   // 12,582,912 B (end 102,346,752)
    __hip_bfloat16* hbuf = qk;                                 // aliases qk+vT+att (50,331,648 B)

    __hip_bfloat16* wqkv_t = wbuf;
    __hip_bfloat16* wo_t   = wbuf + 1769472;
    __hip_bfloat16* w1_t   = wbuf + 2359296;
    __hip_bfloat16* w2_t   = wbuf + 4718592;

    prep_bqkv_kernel<<<108, 256, 0, stream>>>(bq, bk, bv, bqkv);
    embed_ln_kernel<<<2048, 256, 0, stream>>>(tokens, tok_emb, pos_emb, e_s, e_b, x);

    for (int l = 0; l < L_; ++l) {
        prep_layer_kernel<<<1728, 256, 0, stream>>>(Wq, Wk, Wv, Wo, W1, W2, l, wbuf);
        ln_kernel<<<2048, 256, 0, stream>>>(x, l1s + l*768, l1b + l*768, xn);
        gemm_kernel<0><<<2304, 256, 0, stream>>>(xn, wqkv_t, bqkv + l*2304, qk, vT, nullptr, 2304, 768, 18);
        attn_kernel<<<768, 512, 0, stream>>>(qk, vT, att);
        gemm_kernel<2><<<768, 256, 0, stream>>>(att, wo_t, bo + l*768, nullptr, nullptr, x, 768, 768, 6);
        ln_kernel<<<2048, 256, 0, stream>>>(x, l2s + l*768, l2b + l*768, xn);
        gemm_kernel<1><<<3072, 256, 0, stream>>>(xn, w1_t, b1 + l*3072, hbuf, nullptr, nullptr, 3072, 768, 24);
        gemm_kernel<2><<<768, 256, 0, stream>>>(hbuf, w2_t, b2 + l*768, nullptr, nullptr, x, 768, 3072, 6);
    }
    cls_kernel<<<8, 256, 0, stream>>>(x, Wc, bc, (float*)d_out);
}